// Round 5
// baseline (1406.422 us; speedup 1.0000x reference)
//
#include <hip/hip_runtime.h>
#include <hip/hip_bf16.h>
#include <hip/hip_fp16.h>

// B=2, N=1024, C=512, H=8, D=64, m=128, p=8
#define Hh 8
#define Bz 2
#define Nn 1024
#define Cc 512
#define Dd 64
#define Mm 128
#define NS_EPS 1e-4f
#define WHITE_EPS 1e-5f

__device__ __forceinline__ float h2f(__half v) { return __half2float(v); }
__device__ __forceinline__ __half f2h(float v) { return __float2half(v); }

// ---------------------------------------------------------------------------
// K1: QKV GEMM (2048 x 1536 x 512), f32 inputs, masked Q,K,V f16 in (B,N,C).
__global__ __launch_bounds__(256) void qkv_gemm(
    const float* __restrict__ x, const float* __restrict__ w,
    const float* __restrict__ bias, const float* __restrict__ tm,
    __half* __restrict__ Q, __half* __restrict__ K, __half* __restrict__ V) {
  __shared__ float As[64][33];
  __shared__ float Bs[64][33];
  int m0 = blockIdx.x * 64;
  int n0 = blockIdx.y * 64;
  int tid = threadIdx.x;
  int ty = tid >> 4, tx = tid & 15;
  float acc[4][4] = {};
  for (int k0 = 0; k0 < 512; k0 += 32) {
    int r = tid >> 2;
    int kk = (tid & 3) * 8;
    const float* srcA = x + (size_t)(m0 + r) * 512 + k0 + kk;
    const float* srcB = w + (size_t)(n0 + r) * 512 + k0 + kk;
#pragma unroll
    for (int u = 0; u < 8; ++u) As[r][kk + u] = srcA[u];
#pragma unroll
    for (int u = 0; u < 8; ++u) Bs[r][kk + u] = srcB[u];
    __syncthreads();
#pragma unroll
    for (int q = 0; q < 32; ++q) {
      float a[4], b[4];
#pragma unroll
      for (int i = 0; i < 4; ++i) a[i] = As[ty * 4 + i][q];
#pragma unroll
      for (int j = 0; j < 4; ++j) b[j] = Bs[tx * 4 + j][q];
#pragma unroll
      for (int i = 0; i < 4; ++i)
#pragma unroll
        for (int j = 0; j < 4; ++j) acc[i][j] += a[i] * b[j];
    }
    __syncthreads();
  }
#pragma unroll
  for (int i = 0; i < 4; ++i) {
    int row = m0 + ty * 4 + i;
    int b_ = row >> 10, n_ = row & 1023;
    float t = tm[b_ * 1024 + n_];
#pragma unroll
    for (int j = 0; j < 4; ++j) {
      int c3 = n0 + tx * 4 + j;
      float v = (acc[i][j] + bias[c3]) * t;
      int sec = c3 >> 9, ch = c3 & 511;
      __half* dst = (sec == 0) ? Q : (sec == 1 ? K : V);
      dst[(size_t)b_ * (Nn * Cc) + (size_t)n_ * 512 + ch] = f2h(v);
    }
  }
}

// ---------------------------------------------------------------------------
// K2: pooled q_l/k_l (B,H,m,D) f16 + lmask f32. Pool along scrambled t axis:
// q_sp[b,c,u] = Q[b, 2c+u/512, u%512].
__global__ __launch_bounds__(256) void pool_kernel(
    const __half* __restrict__ Q, const __half* __restrict__ K,
    const float* __restrict__ tm, __half* __restrict__ QL,
    __half* __restrict__ KL, float* __restrict__ LM) {
  int idx = blockIdx.x * 256 + threadIdx.x;  // ((b*H+h)*m + j)*D + d
  if (idx >= Bz * Hh * Mm * Dd) return;
  int d = idx & 63;
  int j = (idx >> 6) & 127;
  int h = (idx >> 13) & 7;
  int b = idx >> 16;
  float pm = 0.f;
#pragma unroll
  for (int i = 0; i < 8; ++i) pm += tm[b * 1024 + 8 * j + i];
  pm *= 0.125f;
  float pms = fmaxf(pm, 1e-6f);
  int c = h * 64 + d;
  int n = 2 * c + ((j >= 64) ? 1 : 0);
  int ch0 = 8 * (j & 63);
  size_t base = (size_t)b * (Nn * Cc) + (size_t)n * 512 + ch0;
  float sq = 0.f, sk = 0.f;
#pragma unroll
  for (int i = 0; i < 8; ++i) {
    float t = tm[b * 1024 + 8 * j + i];
    sq += h2f(Q[base + i]) * t;
    sk += h2f(K[base + i]) * t;
  }
  QL[idx] = f2h(sq * 0.125f / pms);
  KL[idx] = f2h(sk * 0.125f / pms);
  if (h == 0 && d == 0) LM[b * Mm + j] = (pm > 0.f) ? 1.f : 0.f;
}

// ---------------------------------------------------------------------------
// K3: W_eps[b,h,i,j] (f32, lives in d_out during NS)
__global__ __launch_bounds__(256) void wbuild_kernel(
    const __half* __restrict__ QL, const __half* __restrict__ KL,
    const float* __restrict__ LM, float* __restrict__ W) {
  int bh = blockIdx.y;
  int b = bh >> 3;
  int i0 = blockIdx.x * 64;
  __shared__ float ks[128][65];
  __shared__ float qs[64][64];
  int tid = threadIdx.x;
  const __half* klb = KL + (size_t)bh * (Mm * Dd);
  const __half* qlb = QL + (size_t)bh * (Mm * Dd);
  for (int e = tid; e < 128 * 64; e += 256) ks[e >> 6][e & 63] = h2f(klb[e]);
  for (int e = tid; e < 64 * 64; e += 256) qs[e >> 6][e & 63] = h2f(qlb[i0 * 64 + e]);
  __syncthreads();
  for (int e = tid; e < 64 * 128; e += 256) {
    int il = e >> 7, j = e & 127;
    int i = i0 + il;
    float s = 0.f;
#pragma unroll
    for (int d = 0; d < 64; ++d) s += fabsf(qs[il][d] - ks[j][d]);
    float wv = expf(-s * 0.25f);
    float pr = LM[b * Mm + i] * LM[b * Mm + j];
    float diag = (i == j) ? 1.f : 0.f;
    wv = wv * pr + diag * (1.f - pr) + diag * NS_EPS;
    W[(size_t)bh * (Mm * Mm) + i * 128 + j] = wv;
  }
}

// ---------------------------------------------------------------------------
// K4: X0 = 2/(fro+1e-8) * W^T  (f32)
__global__ __launch_bounds__(256) void nsinit_kernel(const float* __restrict__ W,
                                                     float* __restrict__ X) {
  int bh = blockIdx.x;
  const float* Wb = W + (size_t)bh * 16384;
  float* Xb = X + (size_t)bh * 16384;
  __shared__ float red[256];
  int tid = threadIdx.x;
  float s = 0.f;
  for (int e = tid; e < 16384; e += 256) { float wv = Wb[e]; s += wv * wv; }
  red[tid] = s;
  __syncthreads();
  for (int off = 128; off > 0; off >>= 1) {
    if (tid < off) red[tid] += red[tid + off];
    __syncthreads();
  }
  float scale = 2.f / (sqrtf(red[0]) + 1e-8f);
  for (int e = tid; e < 16384; e += 256) {
    int i = e >> 7, j = e & 127;
    Xb[e] = scale * Wb[j * 128 + i];
  }
}

// ---------------------------------------------------------------------------
// K5: batched 128x128x128 f32 matmul. mode0: O = 2I - A@B; mode1: O = A@B
__global__ __launch_bounds__(256) void nsmm_kernel(const float* __restrict__ A,
                                                   const float* __restrict__ Bm,
                                                   float* __restrict__ O, int mode) {
  int bh = blockIdx.y;
  int r0 = blockIdx.x * 32;
  const float* Ab = A + (size_t)bh * 16384;
  const float* Bb = Bm + (size_t)bh * 16384;
  float* Ob = O + (size_t)bh * 16384;
  __shared__ float As[32][128];
  int tid = threadIdx.x;
  for (int e = tid; e < 32 * 128; e += 256)
    As[e >> 7][e & 127] = Ab[(size_t)(r0 + (e >> 7)) * 128 + (e & 127)];
  __syncthreads();
  for (int e = tid; e < 32 * 128; e += 256) {
    int il = e >> 7, j = e & 127;
    float acc = 0.f;
#pragma unroll 4
    for (int k = 0; k < 128; ++k) acc += As[il][k] * Bb[(size_t)k * 128 + j];
    int i = r0 + il;
    Ob[(size_t)i * 128 + j] = (mode == 0) ? (((i == j) ? 2.f : 0.f) - acc) : acc;
  }
}

// ---------------------------------------------------------------------------
// K6: fused C_k + K^T V:  KTV[bh,j,d] = sum_n exp(-L1/4)*LM[b,j]*V[b,n,h*64+d]
__global__ __launch_bounds__(256) void ktv_fused(
    const __half* __restrict__ K, const __half* __restrict__ QL,
    const float* __restrict__ LM, const __half* __restrict__ V,
    float* __restrict__ KTV) {
  int bh = blockIdx.y;
  int b = bh >> 3, h = bh & 7;
  int j0 = blockIdx.x * 8;
  __shared__ float qlj[8][64];
  __shared__ float Ks[32][64];
  __shared__ float Vs[32][64];
  __shared__ float lp[8][32];
  int tid = threadIdx.x;
  for (int e = tid; e < 8 * 64; e += 256)
    qlj[e >> 6][e & 63] = h2f(QL[(size_t)bh * 8192 + (size_t)(j0 + (e >> 6)) * 64 + (e & 63)]);
  float acc0 = 0.f, acc1 = 0.f;
  for (int nt = 0; nt < 32; ++nt) {
    int n0 = nt * 32;
    __syncthreads();
    for (int e = tid; e < 2048; e += 256) {
      int nn = e >> 6, d = e & 63;
      size_t gi = (size_t)b * (Nn * Cc) + (size_t)(n0 + nn) * 512 + h * 64 + d;
      Ks[nn][d] = h2f(K[gi]);
      Vs[nn][d] = h2f(V[gi]);
    }
    __syncthreads();
    {
      int jj = tid >> 5, nn = tid & 31;
      float s = 0.f;
#pragma unroll
      for (int d = 0; d < 64; ++d) s += fabsf(Ks[nn][d] - qlj[jj][d]);
      lp[jj][nn] = expf(-s * 0.25f);
    }
    __syncthreads();
    {
      int jj = tid >> 6, d = tid & 63;
      int jj1 = jj + 4;
      float a0 = 0.f, a1 = 0.f;
#pragma unroll 4
      for (int nn = 0; nn < 32; ++nn) {
        a0 += lp[jj][nn] * Vs[nn][d];
        a1 += lp[jj1][nn] * Vs[nn][d];
      }
      acc0 += a0; acc1 += a1;
    }
  }
  {
    int jj = tid >> 6, d = tid & 63;
    KTV[(size_t)bh * 8192 + (size_t)(j0 + jj) * 64 + d] = acc0 * LM[b * 128 + j0 + jj];
    int jj1 = jj + 4;
    KTV[(size_t)bh * 8192 + (size_t)(j0 + jj1) * 64 + d] = acc1 * LM[b * 128 + j0 + jj1];
  }
}

// ---------------------------------------------------------------------------
// K7: CTX[bh,i,d] = sum_j X[bh,i,j] * KTV[bh,j,d]  (f32 in, f16 out)
__global__ __launch_bounds__(256) void ctx_kernel(const float* __restrict__ X,
                                                  const float* __restrict__ KTV,
                                                  __half* __restrict__ CTX) {
  int bh = blockIdx.y;
  int i = blockIdx.x * 4 + (threadIdx.x >> 6);
  int d = threadIdx.x & 63;
  const float* wb = X + (size_t)bh * 16384 + (size_t)i * 128;
  const float* kb = KTV + (size_t)bh * 8192 + d;
  float acc = 0.f;
#pragma unroll 4
  for (int jj = 0; jj < 128; ++jj) acc += wb[jj] * kb[(size_t)jj * 64];
  CTX[(size_t)bh * 8192 + (size_t)i * 64 + d] = f2h(acc);
}

// ---------------------------------------------------------------------------
// K8: scrambled depthwise conv -> VL f16 (in d_ws)
__global__ __launch_bounds__(256) void vlocal_kernel(
    const __half* __restrict__ V, const float* __restrict__ dwc_w,
    const float* __restrict__ dwc_b, const float* __restrict__ tm,
    __half* __restrict__ VL) {
  int idx = blockIdx.x * 256 + threadIdx.x;
  if (idx >= Bz * Nn * Cc) return;
  int c = idx & 511;
  int t = (idx >> 9) & 1023;
  int b = idx >> 19;
  float acc = dwc_b[c];
#pragma unroll
  for (int k = 0; k < 3; ++k) {
    int u = t - 1 + k;
    if (u >= 0 && u < 1024) {
      int n = 2 * c + (u >> 9);
      int ch = u & 511;
      acc += dwc_w[c * 3 + k] * h2f(V[(size_t)b * (Nn * Cc) + (size_t)n * 512 + ch]);
    }
  }
  VL[idx] = f2h(acc * tm[b * 1024 + t]);
}

// ---------------------------------------------------------------------------
// K9: fused whitening stats; recomputes C_q on the fly. Block = (h, jgroup32).
__global__ __launch_bounds__(256) void stats_fused(
    const __half* __restrict__ Q, const __half* __restrict__ KL,
    const float* __restrict__ LM, const float* __restrict__ tm,
    float* __restrict__ MU, float* __restrict__ RS) {
  int h = blockIdx.x >> 2;
  int j0 = (blockIdx.x & 3) * 32;
  __shared__ float klj[32][64];
  __shared__ float qs[32][64];
  __shared__ float racc[32][8][3];
  __shared__ float tacc[8][2];
  __shared__ float tsum[2];
  int tid = threadIdx.x;
  int jl = tid & 31, ns = tid >> 5;
  float p1 = 0.f, p2 = 0.f, p3 = 0.f, pt = 0.f, pt2 = 0.f;
  for (int b = 0; b < 2; ++b) {
    __syncthreads();
    for (int e = tid; e < 2048; e += 256)
      klj[e >> 6][e & 63] =
          h2f(KL[((size_t)(b * 8 + h) * 128 + (j0 + (e >> 6))) * 64 + (e & 63)]);
    __syncthreads();
    float lmj = LM[b * 128 + j0 + jl];
    for (int nt = 0; nt < 32; ++nt) {
      int n0 = nt * 32;
      for (int e = tid; e < 2048; e += 256)
        qs[e >> 6][e & 63] =
            h2f(Q[(size_t)b * (Nn * Cc) + (size_t)(n0 + (e >> 6)) * 512 + h * 64 + (e & 63)]);
      __syncthreads();
#pragma unroll
      for (int w = 0; w < 4; ++w) {
        int nn = ns + w * 8;
        float s = 0.f;
#pragma unroll
        for (int d = 0; d < 64; ++d) s += fabsf(qs[nn][d] - klj[jl][d]);
        float x = expf(-s * 0.25f) * lmj;
        float t = tm[b * 1024 + n0 + nn];
        float xt = x * t;
        p1 += xt; p2 += xt * xt; p3 += xt * t;
        if (jl == 0) { pt += t; pt2 += t * t; }
      }
      __syncthreads();
    }
  }
  racc[jl][ns][0] = p1; racc[jl][ns][1] = p2; racc[jl][ns][2] = p3;
  if (jl == 0) { tacc[ns][0] = pt; tacc[ns][1] = pt2; }
  __syncthreads();
  if (tid == 0) {
    float a = 0.f, c = 0.f;
    for (int q = 0; q < 8; ++q) { a += tacc[q][0]; c += tacc[q][1]; }
    tsum[0] = a; tsum[1] = c;
  }
  __syncthreads();
  if (tid < 32) {
    float s1 = 0.f, s2 = 0.f, s3 = 0.f;
    for (int q = 0; q < 8; ++q) {
      s1 += racc[tid][q][0]; s2 += racc[tid][q][1]; s3 += racc[tid][q][2];
    }
    float valid = fmaxf(tsum[0], 1.f);
    float mu = s1 / valid;
    float var = (s2 - 2.f * mu * s3 + mu * mu * tsum[1]) / valid;
    var = fmaxf(var, 0.f);
    MU[h * 128 + j0 + tid] = mu;
    RS[h * 128 + j0 + tid] = rsqrtf(var + WHITE_EPS);
  }
}

// ---------------------------------------------------------------------------
// K10: fused C_q + whiten + @context, accumulate into VL (f16, in d_ws).
__global__ __launch_bounds__(256) void ga_fused(
    const __half* __restrict__ Q, const __half* __restrict__ KL,
    const float* __restrict__ LM, const float* __restrict__ MU,
    const float* __restrict__ RS, const __half* __restrict__ CTX,
    const float* __restrict__ tm, __half* __restrict__ VL) {
  int bh = blockIdx.y;
  int b = bh >> 3, h = bh & 7;
  int n0 = blockIdx.x * 16;
  __shared__ float kls[128][64];
  __shared__ float qs[16][64];
  __shared__ float P[16][128];
  __shared__ __half ctxs[128][64];
  __shared__ float musr[128][2];
  int tid = threadIdx.x;
  for (int e = tid; e < 8192; e += 256) kls[e >> 6][e & 63] = h2f(KL[(size_t)bh * 8192 + e]);
  for (int e = tid; e < 1024; e += 256)
    qs[e >> 6][e & 63] =
        h2f(Q[(size_t)b * (Nn * Cc) + (size_t)(n0 + (e >> 6)) * 512 + h * 64 + (e & 63)]);
  for (int e = tid; e < 8192; e += 256) ctxs[e >> 6][e & 63] = CTX[(size_t)bh * 8192 + e];
  if (tid < 128) { musr[tid][0] = MU[h * 128 + tid]; musr[tid][1] = RS[h * 128 + tid]; }
  __syncthreads();
  for (int e = tid; e < 2048; e += 256) {
    int nn = e >> 7, j = e & 127;
    float s = 0.f;
#pragma unroll
    for (int d = 0; d < 64; ++d) s += fabsf(qs[nn][d] - kls[j][d]);
    P[nn][j] = expf(-s * 0.25f) * LM[b * 128 + j];
  }
  __syncthreads();
  {
    int nn = tid >> 4, dg = (tid & 15) * 4;
    float a[4] = {};
#pragma unroll 4
    for (int j = 0; j < 128; ++j) {
      float pj = (P[nn][j] - musr[j][0]) * musr[j][1];
#pragma unroll
      for (int q = 0; q < 4; ++q) a[q] += pj * h2f(ctxs[j][dg + q]);
    }
    float t = tm[b * 1024 + n0 + nn];
    size_t base = (size_t)b * (Nn * Cc) + (size_t)(n0 + nn) * 512 + h * 64 + dg;
#pragma unroll
    for (int q = 0; q < 4; ++q)
      VL[base + q] = f2h(h2f(VL[base + q]) + t * t * a[q]);
  }
}

// ---------------------------------------------------------------------------
// K11: projection: out = (VL @ proj_w.T + proj_b) * tm, f32 store.
__global__ __launch_bounds__(256) void proj_gemm(
    const __half* __restrict__ Ain, const float* __restrict__ w,
    const float* __restrict__ bias, const float* __restrict__ tm,
    float* __restrict__ out) {
  __shared__ float As[64][33];
  __shared__ float Bs[64][33];
  int m0 = blockIdx.x * 64;
  int n0 = blockIdx.y * 64;
  int tid = threadIdx.x;
  int ty = tid >> 4, tx = tid & 15;
  float acc[4][4] = {};
  for (int k0 = 0; k0 < 512; k0 += 32) {
    int r = tid >> 2;
    int kk = (tid & 3) * 8;
    const __half* srcA = Ain + (size_t)(m0 + r) * 512 + k0 + kk;
    const float* srcB = w + (size_t)(n0 + r) * 512 + k0 + kk;
#pragma unroll
    for (int u = 0; u < 8; ++u) As[r][kk + u] = h2f(srcA[u]);
#pragma unroll
    for (int u = 0; u < 8; ++u) Bs[r][kk + u] = srcB[u];
    __syncthreads();
#pragma unroll
    for (int q = 0; q < 32; ++q) {
      float a[4], b[4];
#pragma unroll
      for (int i = 0; i < 4; ++i) a[i] = As[ty * 4 + i][q];
#pragma unroll
      for (int j = 0; j < 4; ++j) b[j] = Bs[tx * 4 + j][q];
#pragma unroll
      for (int i = 0; i < 4; ++i)
#pragma unroll
        for (int j = 0; j < 4; ++j) acc[i][j] += a[i] * b[j];
    }
    __syncthreads();
  }
#pragma unroll
  for (int i = 0; i < 4; ++i) {
    int row = m0 + ty * 4 + i;
    int b_ = row >> 10, n_ = row & 1023;
    float t = tm[b_ * 1024 + n_];
#pragma unroll
    for (int j = 0; j < 4; ++j) {
      int co = n0 + tx * 4 + j;
      out[(size_t)row * 512 + co] = (acc[i][j] + bias[co]) * t;
    }
  }
}

// ---------------------------------------------------------------------------
// d_ws: 11.26 MiB. d_out (4 MiB f32): first 2 MiB used as W/T f32 scratch
// during NS (dead before proj_gemm writes the final f32 output).
extern "C" void kernel_launch(void* const* d_in, const int* in_sizes, int n_in,
                              void* d_out, int out_size, void* d_ws, size_t ws_size,
                              hipStream_t stream) {
  const float* x      = (const float*)d_in[0];
  const float* tm     = (const float*)d_in[1];
  const float* qkv_w  = (const float*)d_in[2];
  const float* qkv_b  = (const float*)d_in[3];
  const float* proj_w = (const float*)d_in[4];
  const float* proj_b = (const float*)d_in[5];
  const float* dwc_w  = (const float*)d_in[6];
  const float* dwc_b  = (const float*)d_in[7];
  float* out = (float*)d_out;

  char* wsb = (char*)d_ws;
  __half* Qh  = (__half*)(wsb + 0);          // 2 MiB
  __half* Kh  = (__half*)(wsb + 2097152);    // 2 MiB
  __half* Vh  = (__half*)(wsb + 4194304);    // 2 MiB
  __half* VLh = (__half*)(wsb + 6291456);    // 2 MiB
  __half* QLh = (__half*)(wsb + 8388608);    // 256 KiB
  __half* KLh = (__half*)(wsb + 8650752);    // 256 KiB
  float*  LM  = (float*)(wsb + 8912896);     // 1 KiB
  float*  MU  = (float*)(wsb + 8913920);     // 4 KiB
  float*  RS  = (float*)(wsb + 8918016);     // 4 KiB
  float*  KTV = (float*)(wsb + 8922112);     // 512 KiB
  __half* CTX = (__half*)(wsb + 9446400);    // 256 KiB
  float*  XA  = (float*)(wsb + 9708544);     // 1 MiB
  float*  XB  = (float*)(wsb + 10757120);    // 1 MiB (end 11,805,696 B)

  char* ob = (char*)d_out;
  float* Wf = (float*)ob;              // 1 MiB (NS scratch)
  float* Tf = (float*)(ob + 1048576);  // 1 MiB (NS scratch)

  qkv_gemm<<<dim3(32, 24), 256, 0, stream>>>(x, qkv_w, qkv_b, tm, Qh, Kh, Vh);
  pool_kernel<<<512, 256, 0, stream>>>(Qh, Kh, tm, QLh, KLh, LM);
  wbuild_kernel<<<dim3(2, 16), 256, 0, stream>>>(QLh, KLh, LM, Wf);
  nsinit_kernel<<<16, 256, 0, stream>>>(Wf, XA);
  float* Xc = XA;
  float* Xn = XB;
  for (int it = 0; it < 5; ++it) {
    nsmm_kernel<<<dim3(4, 16), 256, 0, stream>>>(Wf, Xc, Tf, 0);
    nsmm_kernel<<<dim3(4, 16), 256, 0, stream>>>(Xc, Tf, Xn, 1);
    float* tswap = Xc; Xc = Xn; Xn = tswap;
  }
  ktv_fused<<<dim3(16, 16), 256, 0, stream>>>(Kh, QLh, LM, Vh, KTV);
  ctx_kernel<<<dim3(32, 16), 256, 0, stream>>>(Xc, KTV, CTX);
  vlocal_kernel<<<4096, 256, 0, stream>>>(Vh, dwc_w, dwc_b, tm, VLh);
  stats_fused<<<32, 256, 0, stream>>>(Qh, KLh, LM, tm, MU, RS);
  ga_fused<<<dim3(64, 16), 256, 0, stream>>>(Qh, KLh, LM, MU, RS, CTX, tm, VLh);
  proj_gemm<<<dim3(32, 8), 256, 0, stream>>>(VLh, proj_w, proj_b, tm, out);
}

// Round 6
// 804.064 us; speedup vs baseline: 1.7491x; 1.7491x over previous
//
#include <hip/hip_runtime.h>
#include <hip/hip_bf16.h>
#include <hip/hip_fp16.h>

// B=2, N=1024, C=512, H=8, D=64, m=128, p=8
#define Hh 8
#define Bz 2
#define Nn 1024
#define Cc 512
#define Dd 64
#define Mm 128
#define NS_EPS 1e-4f
#define WHITE_EPS 1e-5f

__device__ __forceinline__ float h2f(__half v) { return __half2float(v); }
__device__ __forceinline__ __half f2h(float v) { return __float2half(v); }

// ---------------------------------------------------------------------------
// K1: QKV GEMM (2048 x 1536 x 512), f32 inputs, masked Q,K,V f16 in (B,N,C).
__global__ __launch_bounds__(256) void qkv_gemm(
    const float* __restrict__ x, const float* __restrict__ w,
    const float* __restrict__ bias, const float* __restrict__ tm,
    __half* __restrict__ Q, __half* __restrict__ K, __half* __restrict__ V) {
  __shared__ float As[64][33];
  __shared__ float Bs[64][33];
  int m0 = blockIdx.x * 64;
  int n0 = blockIdx.y * 64;
  int tid = threadIdx.x;
  int ty = tid >> 4, tx = tid & 15;
  float acc[4][4] = {};
  for (int k0 = 0; k0 < 512; k0 += 32) {
    int r = tid >> 2;
    int kk = (tid & 3) * 8;
    const float* srcA = x + (size_t)(m0 + r) * 512 + k0 + kk;
    const float* srcB = w + (size_t)(n0 + r) * 512 + k0 + kk;
#pragma unroll
    for (int u = 0; u < 8; ++u) As[r][kk + u] = srcA[u];
#pragma unroll
    for (int u = 0; u < 8; ++u) Bs[r][kk + u] = srcB[u];
    __syncthreads();
#pragma unroll
    for (int q = 0; q < 32; ++q) {
      float a[4], b[4];
#pragma unroll
      for (int i = 0; i < 4; ++i) a[i] = As[ty * 4 + i][q];
#pragma unroll
      for (int j = 0; j < 4; ++j) b[j] = Bs[tx * 4 + j][q];
#pragma unroll
      for (int i = 0; i < 4; ++i)
#pragma unroll
        for (int j = 0; j < 4; ++j) acc[i][j] += a[i] * b[j];
    }
    __syncthreads();
  }
#pragma unroll
  for (int i = 0; i < 4; ++i) {
    int row = m0 + ty * 4 + i;
    int b_ = row >> 10, n_ = row & 1023;
    float t = tm[b_ * 1024 + n_];
#pragma unroll
    for (int j = 0; j < 4; ++j) {
      int c3 = n0 + tx * 4 + j;
      float v = (acc[i][j] + bias[c3]) * t;
      int sec = c3 >> 9, ch = c3 & 511;
      __half* dst = (sec == 0) ? Q : (sec == 1 ? K : V);
      dst[(size_t)b_ * (Nn * Cc) + (size_t)n_ * 512 + ch] = f2h(v);
    }
  }
}

// ---------------------------------------------------------------------------
// K2: pool v2 — block per (b,h,u-tile of 64). Coalesced row staging.
// q_sp[b,c,u] = Q[b, 2c+(u>>9), u&511], c = h*64+d.
__global__ __launch_bounds__(256) void pool_kernel(
    const __half* __restrict__ Q, const __half* __restrict__ K,
    const float* __restrict__ tm, __half* __restrict__ QL,
    __half* __restrict__ KL, float* __restrict__ LM) {
  int ut = blockIdx.x;       // 0..15
  int bh = blockIdx.y;       // b*8+h
  int b = bh >> 3, h = bh & 7;
  int u0 = ut * 64;
  int delta = u0 >> 9;
  int ch0 = u0 & 511;
  __shared__ float Qs[64][65];
  __shared__ float Ks[64][65];
  int tid = threadIdx.x;
  for (int e = tid; e < 4096; e += 256) {
    int d = e >> 6, uu = e & 63;
    int row = 2 * (h * 64 + d) + delta;
    size_t gi = (size_t)b * (Nn * Cc) + (size_t)row * 512 + ch0 + uu;
    Qs[d][uu] = h2f(Q[gi]);
    Ks[d][uu] = h2f(K[gi]);
  }
  __syncthreads();
  int d = tid & 63, s = tid >> 6;
#pragma unroll
  for (int jr = 0; jr < 2; ++jr) {
    int jl = s + 4 * jr;         // 0..7
    int j = ut * 8 + jl;
    float pm = 0.f, sq = 0.f, sk = 0.f;
#pragma unroll
    for (int i = 0; i < 8; ++i) {
      float t = tm[b * 1024 + 8 * j + i];
      pm += t;
      sq += Qs[d][8 * jl + i] * t;
      sk += Ks[d][8 * jl + i] * t;
    }
    pm *= 0.125f;
    float pms = fmaxf(pm, 1e-6f);
    size_t oi = ((size_t)bh * 128 + j) * 64 + d;
    QL[oi] = f2h(sq * 0.125f / pms);
    KL[oi] = f2h(sk * 0.125f / pms);
    if (h == 0 && d == 0) LM[b * 128 + j] = (pm > 0.f) ? 1.f : 0.f;
  }
}

// ---------------------------------------------------------------------------
// K3: W_eps[b,h,i,j] (f32, lives in d_out during NS)
__global__ __launch_bounds__(256) void wbuild_kernel(
    const __half* __restrict__ QL, const __half* __restrict__ KL,
    const float* __restrict__ LM, float* __restrict__ W) {
  int bh = blockIdx.y;
  int b = bh >> 3;
  int i0 = blockIdx.x * 64;
  __shared__ float ks[128][65];
  __shared__ float qs[64][65];
  int tid = threadIdx.x;
  const __half* klb = KL + (size_t)bh * (Mm * Dd);
  const __half* qlb = QL + (size_t)bh * (Mm * Dd);
  for (int e = tid; e < 128 * 64; e += 256) ks[e >> 6][e & 63] = h2f(klb[e]);
  for (int e = tid; e < 64 * 64; e += 256) qs[e >> 6][e & 63] = h2f(qlb[i0 * 64 + e]);
  __syncthreads();
  for (int e = tid; e < 64 * 128; e += 256) {
    int il = e >> 7, j = e & 127;
    int i = i0 + il;
    float s = 0.f;
#pragma unroll
    for (int d = 0; d < 64; ++d) s += fabsf(qs[il][d] - ks[j][d]);
    float wv = expf(-s * 0.25f);
    float pr = LM[b * Mm + i] * LM[b * Mm + j];
    float diag = (i == j) ? 1.f : 0.f;
    wv = wv * pr + diag * (1.f - pr) + diag * NS_EPS;
    W[(size_t)bh * (Mm * Mm) + i * 128 + j] = wv;
  }
}

// ---------------------------------------------------------------------------
// K4: X0 = 2/(fro+1e-8) * W^T  (f32)
__global__ __launch_bounds__(256) void nsinit_kernel(const float* __restrict__ W,
                                                     float* __restrict__ X) {
  int bh = blockIdx.x;
  const float* Wb = W + (size_t)bh * 16384;
  float* Xb = X + (size_t)bh * 16384;
  __shared__ float red[256];
  int tid = threadIdx.x;
  float s = 0.f;
  for (int e = tid; e < 16384; e += 256) { float wv = Wb[e]; s += wv * wv; }
  red[tid] = s;
  __syncthreads();
  for (int off = 128; off > 0; off >>= 1) {
    if (tid < off) red[tid] += red[tid + off];
    __syncthreads();
  }
  float scale = 2.f / (sqrtf(red[0]) + 1e-8f);
  for (int e = tid; e < 16384; e += 256) {
    int i = e >> 7, j = e & 127;
    Xb[e] = scale * Wb[j * 128 + i];
  }
}

// ---------------------------------------------------------------------------
// K5: nsmm v2 — LDS-staged A and B tiles. mode0: O = 2I - A@B; mode1: O = A@B
__global__ __launch_bounds__(256) void nsmm_kernel(const float* __restrict__ A,
                                                   const float* __restrict__ Bm,
                                                   float* __restrict__ O, int mode) {
  int bh = blockIdx.y;
  int R0 = blockIdx.x * 32;
  const float* Ab = A + (size_t)bh * 16384;
  const float* Bb = Bm + (size_t)bh * 16384;
  float* Ob = O + (size_t)bh * 16384;
  __shared__ float As[32][33];
  __shared__ float Bs[32][132];
  int tid = threadIdx.x;
  int j0 = (tid & 31) * 4, r0 = (tid >> 5) * 4;
  float acc[4][4] = {};
  for (int kt = 0; kt < 4; ++kt) {
    __syncthreads();
    for (int e = tid; e < 1024; e += 256) {
      int r = e >> 5, k = e & 31;
      As[r][k] = Ab[(size_t)(R0 + r) * 128 + kt * 32 + k];
    }
    for (int e = tid; e < 4096; e += 256) {
      int k = e >> 7, j = e & 127;
      Bs[k][j] = Bb[(size_t)(kt * 32 + k) * 128 + j];
    }
    __syncthreads();
#pragma unroll 8
    for (int k = 0; k < 32; ++k) {
      float b0 = Bs[k][j0], b1 = Bs[k][j0 + 1], b2 = Bs[k][j0 + 2], b3 = Bs[k][j0 + 3];
#pragma unroll
      for (int i = 0; i < 4; ++i) {
        float a = As[r0 + i][k];
        acc[i][0] += a * b0; acc[i][1] += a * b1;
        acc[i][2] += a * b2; acc[i][3] += a * b3;
      }
    }
  }
#pragma unroll
  for (int i = 0; i < 4; ++i) {
    int gi = R0 + r0 + i;
#pragma unroll
    for (int q = 0; q < 4; ++q) {
      int gj = j0 + q;
      float v = acc[i][q];
      if (mode == 0) v = ((gi == gj) ? 2.f : 0.f) - v;
      Ob[(size_t)gi * 128 + gj] = v;
    }
  }
}

// ---------------------------------------------------------------------------
// K6: ktv v2 — fused C_k + K^T V, padded LDS, 128 blocks.
// KTV[bh,j,d] = sum_n exp(-L1(K[n],QL[j])/4) * LM[j] * V[n,d]
__global__ __launch_bounds__(256) void ktv_fused(
    const __half* __restrict__ K, const __half* __restrict__ QL,
    const float* __restrict__ LM, const __half* __restrict__ V,
    float* __restrict__ KTV) {
  int bh = blockIdx.y;
  int b = bh >> 3, h = bh & 7;
  int j0 = blockIdx.x * 16;
  __shared__ float qls[16][65];
  __shared__ float Ks[32][65];
  __shared__ float Vs[32][65];
  __shared__ float P[32][17];
  int tid = threadIdx.x;
  for (int e = tid; e < 1024; e += 256)
    qls[e >> 6][e & 63] = h2f(QL[(size_t)bh * 8192 + (size_t)(j0 + (e >> 6)) * 64 + (e & 63)]);
  float acc[4] = {};
  for (int nt = 0; nt < 32; ++nt) {
    int n0 = nt * 32;
    __syncthreads();
    for (int e = tid; e < 2048; e += 256) {
      int nn = e >> 6, d = e & 63;
      size_t gi = (size_t)b * (Nn * Cc) + (size_t)(n0 + nn) * 512 + h * 64 + d;
      Ks[nn][d] = h2f(K[gi]);
      Vs[nn][d] = h2f(V[gi]);
    }
    __syncthreads();
#pragma unroll
    for (int r = 0; r < 2; ++r) {
      int e = tid + 256 * r;
      int j = e >> 5, n = e & 31;
      float s = 0.f;
#pragma unroll
      for (int d = 0; d < 64; ++d) s += fabsf(Ks[n][d] - qls[j][d]);
      P[n][j] = expf(-s * 0.25f);
    }
    __syncthreads();
    {
      int d = tid & 63;
#pragma unroll
      for (int r = 0; r < 4; ++r) {
        int j = (tid >> 6) + 4 * r;
        float a = 0.f;
#pragma unroll 8
        for (int n = 0; n < 32; ++n) a += P[n][j] * Vs[n][d];
        acc[r] += a;
      }
    }
  }
  {
    int d = tid & 63;
#pragma unroll
    for (int r = 0; r < 4; ++r) {
      int j = (tid >> 6) + 4 * r;
      KTV[(size_t)bh * 8192 + (size_t)(j0 + j) * 64 + d] = acc[r] * LM[b * 128 + j0 + j];
    }
  }
}

// ---------------------------------------------------------------------------
// K7: CTX[bh,i,d] = sum_j X[bh,i,j] * KTV[bh,j,d]  (f32 in, f16 out)
__global__ __launch_bounds__(256) void ctx_kernel(const float* __restrict__ X,
                                                  const float* __restrict__ KTV,
                                                  __half* __restrict__ CTX) {
  int bh = blockIdx.y;
  int i = blockIdx.x * 4 + (threadIdx.x >> 6);
  int d = threadIdx.x & 63;
  const float* wb = X + (size_t)bh * 16384 + (size_t)i * 128;
  const float* kb = KTV + (size_t)bh * 8192 + d;
  float acc = 0.f;
#pragma unroll 4
  for (int jj = 0; jj < 128; ++jj) acc += wb[jj] * kb[(size_t)jj * 64];
  CTX[(size_t)bh * 8192 + (size_t)i * 64 + d] = f2h(acc);
}

// ---------------------------------------------------------------------------
// K8: stats_partial — per (n-tile, bh) block: 16x128 P-tile, per-j partials.
// PS[((b*64+nt)*8+h)*384 + j*3 + {0,1,2}] = {sum x*t, sum (x*t)^2, sum x*t^2}
__global__ __launch_bounds__(256) void stats_partial(
    const __half* __restrict__ Q, const __half* __restrict__ KL,
    const float* __restrict__ LM, const float* __restrict__ tm,
    float* __restrict__ PS) {
  int nt = blockIdx.x;
  int bh = blockIdx.y;
  int b = bh >> 3, h = bh & 7;
  int n0 = nt * 16;
  __shared__ float kls[128][65];
  __shared__ float qs[16][65];
  __shared__ float part[256][3];
  int tid = threadIdx.x;
  for (int e = tid; e < 8192; e += 256) kls[e >> 6][e & 63] = h2f(KL[(size_t)bh * 8192 + e]);
  for (int e = tid; e < 1024; e += 256)
    qs[e >> 6][e & 63] =
        h2f(Q[(size_t)b * (Nn * Cc) + (size_t)(n0 + (e >> 6)) * 512 + h * 64 + (e & 63)]);
  __syncthreads();
  int j = tid & 127, nb = tid >> 7;
  float lmj = LM[b * 128 + j];
  float s1 = 0.f, s2 = 0.f, s3 = 0.f;
#pragma unroll
  for (int r = 0; r < 8; ++r) {
    int nn = nb * 8 + r;
    float s = 0.f;
#pragma unroll
    for (int d = 0; d < 64; ++d) s += fabsf(qs[nn][d] - kls[j][d]);
    float xv = expf(-s * 0.25f) * lmj;
    float t = tm[b * 1024 + n0 + nn];
    float xt = xv * t;
    s1 += xt; s2 += xt * xt; s3 += xt * t;
  }
  part[tid][0] = s1; part[tid][1] = s2; part[tid][2] = s3;
  __syncthreads();
  if (tid < 128) {
    float a = part[tid][0] + part[tid + 128][0];
    float c = part[tid][1] + part[tid + 128][1];
    float e = part[tid][2] + part[tid + 128][2];
    size_t base = ((size_t)(b * 64 + nt) * 8 + h) * 384 + tid * 3;
    PS[base] = a; PS[base + 1] = c; PS[base + 2] = e;
  }
}

// ---------------------------------------------------------------------------
// K9: stats_final — reduce PS over 128 (b,nt) tiles per (h,j); compute mu/rstd.
__global__ __launch_bounds__(256) void stats_final(const float* __restrict__ PS,
                                                   const float* __restrict__ tm,
                                                   float* __restrict__ MU,
                                                   float* __restrict__ RS) {
  __shared__ float red[256][2];
  __shared__ float ts0, ts1;
  int tid = threadIdx.x;
  float a = 0.f, c = 0.f;
  for (int i = tid; i < 2048; i += 256) { float t = tm[i]; a += t; c += t * t; }
  red[tid][0] = a; red[tid][1] = c;
  __syncthreads();
  for (int off = 128; off > 0; off >>= 1) {
    if (tid < off) { red[tid][0] += red[tid + off][0]; red[tid][1] += red[tid + off][1]; }
    __syncthreads();
  }
  if (tid == 0) { ts0 = red[0][0]; ts1 = red[0][1]; }
  __syncthreads();
  int hj = blockIdx.x * 256 + tid;
  int h = hj >> 7, j = hj & 127;
  float s1 = 0.f, s2 = 0.f, s3 = 0.f;
  for (int bnt = 0; bnt < 128; ++bnt) {
    const float* p = PS + ((size_t)bnt * 8 + h) * 384 + j * 3;
    s1 += p[0]; s2 += p[1]; s3 += p[2];
  }
  float valid = fmaxf(ts0, 1.f);
  float mu = s1 / valid;
  float var = (s2 - 2.f * mu * s3 + mu * mu * ts1) / valid;
  var = fmaxf(var, 0.f);
  MU[hj] = mu;
  RS[hj] = rsqrtf(var + WHITE_EPS);
}

// ---------------------------------------------------------------------------
// K10: scrambled depthwise conv -> VL f16 (in d_ws)
__global__ __launch_bounds__(256) void vlocal_kernel(
    const __half* __restrict__ V, const float* __restrict__ dwc_w,
    const float* __restrict__ dwc_b, const float* __restrict__ tm,
    __half* __restrict__ VL) {
  int idx = blockIdx.x * 256 + threadIdx.x;
  if (idx >= Bz * Nn * Cc) return;
  int c = idx & 511;
  int t = (idx >> 9) & 1023;
  int b = idx >> 19;
  float acc = dwc_b[c];
#pragma unroll
  for (int k = 0; k < 3; ++k) {
    int u = t - 1 + k;
    if (u >= 0 && u < 1024) {
      int n = 2 * c + (u >> 9);
      int ch = u & 511;
      acc += dwc_w[c * 3 + k] * h2f(V[(size_t)b * (Nn * Cc) + (size_t)n * 512 + ch]);
    }
  }
  VL[idx] = f2h(acc * tm[b * 1024 + t]);
}

// ---------------------------------------------------------------------------
// K11: ga v2 — fused C_q + whiten + @context, accumulate into VL. Padded LDS.
__global__ __launch_bounds__(256) void ga_fused(
    const __half* __restrict__ Q, const __half* __restrict__ KL,
    const float* __restrict__ LM, const float* __restrict__ MU,
    const float* __restrict__ RS, const __half* __restrict__ CTXg,
    const float* __restrict__ tm, __half* __restrict__ VL) {
  int bh = blockIdx.y;
  int b = bh >> 3, h = bh & 7;
  int n0 = blockIdx.x * 16;
  __shared__ float kls[128][65];
  __shared__ float qs[16][65];
  __shared__ float P[16][129];
  __shared__ __half2 ctx2[128][32];
  __shared__ float musr[128][2];
  int tid = threadIdx.x;
  for (int e = tid; e < 8192; e += 256) kls[e >> 6][e & 63] = h2f(KL[(size_t)bh * 8192 + e]);
  for (int e = tid; e < 1024; e += 256)
    qs[e >> 6][e & 63] =
        h2f(Q[(size_t)b * (Nn * Cc) + (size_t)(n0 + (e >> 6)) * 512 + h * 64 + (e & 63)]);
  {
    const __half2* cg = (const __half2*)(CTXg + (size_t)bh * 8192);
    for (int e = tid; e < 4096; e += 256) ctx2[e >> 5][e & 31] = cg[e];
  }
  if (tid < 128) { musr[tid][0] = MU[h * 128 + tid]; musr[tid][1] = RS[h * 128 + tid]; }
  __syncthreads();
  {
    int j = tid & 127, nb = tid >> 7;
    float lmj = LM[b * 128 + j];
#pragma unroll
    for (int r = 0; r < 8; ++r) {
      int nn = nb * 8 + r;
      float s = 0.f;
#pragma unroll
      for (int d = 0; d < 64; ++d) s += fabsf(qs[nn][d] - kls[j][d]);
      P[nn][j] = expf(-s * 0.25f) * lmj;
    }
  }
  __syncthreads();
  {
    int nn = tid >> 4, dq = tid & 15;
    float a0 = 0.f, a1 = 0.f, a2 = 0.f, a3 = 0.f;
#pragma unroll 4
    for (int j = 0; j < 128; ++j) {
      float pj = (P[nn][j] - musr[j][0]) * musr[j][1];
      __half2 c01 = ctx2[j][dq * 2];
      __half2 c23 = ctx2[j][dq * 2 + 1];
      a0 += pj * h2f(c01.x); a1 += pj * h2f(c01.y);
      a2 += pj * h2f(c23.x); a3 += pj * h2f(c23.y);
    }
    float t = tm[b * 1024 + n0 + nn];
    float t2 = t * t;
    size_t base = (size_t)b * (Nn * Cc) + (size_t)(n0 + nn) * 512 + h * 64 + dq * 4;
    VL[base] = f2h(h2f(VL[base]) + t2 * a0);
    VL[base + 1] = f2h(h2f(VL[base + 1]) + t2 * a1);
    VL[base + 2] = f2h(h2f(VL[base + 2]) + t2 * a2);
    VL[base + 3] = f2h(h2f(VL[base + 3]) + t2 * a3);
  }
}

// ---------------------------------------------------------------------------
// K12: projection: out = (VL @ proj_w.T + proj_b) * tm, f32 store.
__global__ __launch_bounds__(256) void proj_gemm(
    const __half* __restrict__ Ain, const float* __restrict__ w,
    const float* __restrict__ bias, const float* __restrict__ tm,
    float* __restrict__ out) {
  __shared__ float As[64][33];
  __shared__ float Bs[64][33];
  int m0 = blockIdx.x * 64;
  int n0 = blockIdx.y * 64;
  int tid = threadIdx.x;
  int ty = tid >> 4, tx = tid & 15;
  float acc[4][4] = {};
  for (int k0 = 0; k0 < 512; k0 += 32) {
    int r = tid >> 2;
    int kk = (tid & 3) * 8;
    const __half* srcA = Ain + (size_t)(m0 + r) * 512 + k0 + kk;
    const float* srcB = w + (size_t)(n0 + r) * 512 + k0 + kk;
#pragma unroll
    for (int u = 0; u < 8; ++u) As[r][kk + u] = h2f(srcA[u]);
#pragma unroll
    for (int u = 0; u < 8; ++u) Bs[r][kk + u] = srcB[u];
    __syncthreads();
#pragma unroll
    for (int q = 0; q < 32; ++q) {
      float a[4], b[4];
#pragma unroll
      for (int i = 0; i < 4; ++i) a[i] = As[ty * 4 + i][q];
#pragma unroll
      for (int j = 0; j < 4; ++j) b[j] = Bs[tx * 4 + j][q];
#pragma unroll
      for (int i = 0; i < 4; ++i)
#pragma unroll
        for (int j = 0; j < 4; ++j) acc[i][j] += a[i] * b[j];
    }
    __syncthreads();
  }
#pragma unroll
  for (int i = 0; i < 4; ++i) {
    int row = m0 + ty * 4 + i;
    int b_ = row >> 10, n_ = row & 1023;
    float t = tm[b_ * 1024 + n_];
#pragma unroll
    for (int j = 0; j < 4; ++j) {
      int co = n0 + tx * 4 + j;
      out[(size_t)row * 512 + co] = (acc[i][j] + bias[co]) * t;
    }
  }
}

// ---------------------------------------------------------------------------
// d_ws: 11.26 MiB high-water (proven safe). PS (1.5 MiB) overlays dead XA+XB
// after ctx. d_out: first 2 MiB = W/T f32 NS scratch; proj writes last.
extern "C" void kernel_launch(void* const* d_in, const int* in_sizes, int n_in,
                              void* d_out, int out_size, void* d_ws, size_t ws_size,
                              hipStream_t stream) {
  const float* x      = (const float*)d_in[0];
  const float* tm     = (const float*)d_in[1];
  const float* qkv_w  = (const float*)d_in[2];
  const float* qkv_b  = (const float*)d_in[3];
  const float* proj_w = (const float*)d_in[4];
  const float* proj_b = (const float*)d_in[5];
  const float* dwc_w  = (const float*)d_in[6];
  const float* dwc_b  = (const float*)d_in[7];
  float* out = (float*)d_out;

  char* wsb = (char*)d_ws;
  __half* Qh  = (__half*)(wsb + 0);          // 2 MiB
  __half* Kh  = (__half*)(wsb + 2097152);    // 2 MiB
  __half* Vh  = (__half*)(wsb + 4194304);    // 2 MiB
  __half* VLh = (__half*)(wsb + 6291456);    // 2 MiB
  __half* QLh = (__half*)(wsb + 8388608);    // 256 KiB
  __half* KLh = (__half*)(wsb + 8650752);    // 256 KiB
  float*  LM  = (float*)(wsb + 8912896);     // 1 KiB
  float*  MU  = (float*)(wsb + 8913920);     // 4 KiB
  float*  RS  = (float*)(wsb + 8918016);     // 4 KiB
  float*  KTV = (float*)(wsb + 8922112);     // 512 KiB
  __half* CTX = (__half*)(wsb + 9446400);    // 256 KiB
  float*  XA  = (float*)(wsb + 9708544);     // 1 MiB
  float*  XB  = (float*)(wsb + 10757120);    // 1 MiB (end 11,805,696)
  float*  PS  = (float*)(wsb + 9708544);     // 1.5 MiB (overlays XA+XB after ctx)

  char* ob = (char*)d_out;
  float* Wf = (float*)ob;              // 1 MiB (NS scratch)
  float* Tf = (float*)(ob + 1048576);  // 1 MiB (NS scratch)

  qkv_gemm<<<dim3(32, 24), 256, 0, stream>>>(x, qkv_w, qkv_b, tm, Qh, Kh, Vh);
  pool_kernel<<<dim3(16, 16), 256, 0, stream>>>(Qh, Kh, tm, QLh, KLh, LM);
  wbuild_kernel<<<dim3(2, 16), 256, 0, stream>>>(QLh, KLh, LM, Wf);
  nsinit_kernel<<<16, 256, 0, stream>>>(Wf, XA);
  float* Xc = XA;
  float* Xn = XB;
  for (int it = 0; it < 5; ++it) {
    nsmm_kernel<<<dim3(4, 16), 256, 0, stream>>>(Wf, Xc, Tf, 0);
    nsmm_kernel<<<dim3(4, 16), 256, 0, stream>>>(Xc, Tf, Xn, 1);
    float* tswap = Xc; Xc = Xn; Xn = tswap;
  }
  ktv_fused<<<dim3(8, 16), 256, 0, stream>>>(Kh, QLh, LM, Vh, KTV);
  ctx_kernel<<<dim3(32, 16), 256, 0, stream>>>(Xc, KTV, CTX);
  // XA/XB now dead -> PS region free
  stats_partial<<<dim3(64, 16), 256, 0, stream>>>(Qh, KLh, LM, tm, PS);
  stats_final<<<4, 256, 0, stream>>>(PS, tm, MU, RS);
  vlocal_kernel<<<4096, 256, 0, stream>>>(Vh, dwc_w, dwc_b, tm, VLh);
  ga_fused<<<dim3(64, 16), 256, 0, stream>>>(Qh, KLh, LM, MU, RS, CTX, tm, VLh);
  proj_gemm<<<dim3(32, 8), 256, 0, stream>>>(VLh, proj_w, proj_b, tm, out);
}

// Round 7
// 594.151 us; speedup vs baseline: 2.3671x; 1.3533x over previous
//
#include <hip/hip_runtime.h>
#include <hip/hip_bf16.h>
#include <hip/hip_fp16.h>

// B=2, N=1024, C=512, H=8, D=64, m=128, p=8
#define Hh 8
#define Bz 2
#define Nn 1024
#define Cc 512
#define Dd 64
#define Mm 128
#define NS_EPS 1e-4f
#define WHITE_EPS 1e-5f

__device__ __forceinline__ float h2f(__half v) { return __half2float(v); }
__device__ __forceinline__ __half f2h(float v) { return __float2half(v); }

// ---------------------------------------------------------------------------
// K1: QKV GEMM (2048 x 1536 x 512), f32 inputs, masked Q,K,V f16 in (B,N,C).
__global__ __launch_bounds__(256) void qkv_gemm(
    const float* __restrict__ x, const float* __restrict__ w,
    const float* __restrict__ bias, const float* __restrict__ tm,
    __half* __restrict__ Q, __half* __restrict__ K, __half* __restrict__ V) {
  __shared__ float As[64][33];
  __shared__ float Bs[64][33];
  int m0 = blockIdx.x * 64;
  int n0 = blockIdx.y * 64;
  int tid = threadIdx.x;
  int ty = tid >> 4, tx = tid & 15;
  float acc[4][4] = {};
  for (int k0 = 0; k0 < 512; k0 += 32) {
    int r = tid >> 2;
    int kk = (tid & 3) * 8;
    const float* srcA = x + (size_t)(m0 + r) * 512 + k0 + kk;
    const float* srcB = w + (size_t)(n0 + r) * 512 + k0 + kk;
#pragma unroll
    for (int u = 0; u < 8; ++u) As[r][kk + u] = srcA[u];
#pragma unroll
    for (int u = 0; u < 8; ++u) Bs[r][kk + u] = srcB[u];
    __syncthreads();
#pragma unroll
    for (int q = 0; q < 32; ++q) {
      float a[4], b[4];
#pragma unroll
      for (int i = 0; i < 4; ++i) a[i] = As[ty * 4 + i][q];
#pragma unroll
      for (int j = 0; j < 4; ++j) b[j] = Bs[tx * 4 + j][q];
#pragma unroll
      for (int i = 0; i < 4; ++i)
#pragma unroll
        for (int j = 0; j < 4; ++j) acc[i][j] += a[i] * b[j];
    }
    __syncthreads();
  }
#pragma unroll
  for (int i = 0; i < 4; ++i) {
    int row = m0 + ty * 4 + i;
    int b_ = row >> 10, n_ = row & 1023;
    float t = tm[b_ * 1024 + n_];
#pragma unroll
    for (int j = 0; j < 4; ++j) {
      int c3 = n0 + tx * 4 + j;
      float v = (acc[i][j] + bias[c3]) * t;
      int sec = c3 >> 9, ch = c3 & 511;
      __half* dst = (sec == 0) ? Q : (sec == 1 ? K : V);
      dst[(size_t)b_ * (Nn * Cc) + (size_t)n_ * 512 + ch] = f2h(v);
    }
  }
}

// ---------------------------------------------------------------------------
// K2: pool — block per (b,h,u-tile of 64). Coalesced row staging.
__global__ __launch_bounds__(256) void pool_kernel(
    const __half* __restrict__ Q, const __half* __restrict__ K,
    const float* __restrict__ tm, __half* __restrict__ QL,
    __half* __restrict__ KL, float* __restrict__ LM) {
  int ut = blockIdx.x;
  int bh = blockIdx.y;
  int b = bh >> 3, h = bh & 7;
  int u0 = ut * 64;
  int delta = u0 >> 9;
  int ch0 = u0 & 511;
  __shared__ float Qs[64][65];
  __shared__ float Ks[64][65];
  int tid = threadIdx.x;
  for (int e = tid; e < 4096; e += 256) {
    int d = e >> 6, uu = e & 63;
    int row = 2 * (h * 64 + d) + delta;
    size_t gi = (size_t)b * (Nn * Cc) + (size_t)row * 512 + ch0 + uu;
    Qs[d][uu] = h2f(Q[gi]);
    Ks[d][uu] = h2f(K[gi]);
  }
  __syncthreads();
  int d = tid & 63, s = tid >> 6;
#pragma unroll
  for (int jr = 0; jr < 2; ++jr) {
    int jl = s + 4 * jr;
    int j = ut * 8 + jl;
    float pm = 0.f, sq = 0.f, sk = 0.f;
#pragma unroll
    for (int i = 0; i < 8; ++i) {
      float t = tm[b * 1024 + 8 * j + i];
      pm += t;
      sq += Qs[d][8 * jl + i] * t;
      sk += Ks[d][8 * jl + i] * t;
    }
    pm *= 0.125f;
    float pms = fmaxf(pm, 1e-6f);
    size_t oi = ((size_t)bh * 128 + j) * 64 + d;
    QL[oi] = f2h(sq * 0.125f / pms);
    KL[oi] = f2h(sk * 0.125f / pms);
    if (h == 0 && d == 0) LM[b * 128 + j] = (pm > 0.f) ? 1.f : 0.f;
  }
}

// ---------------------------------------------------------------------------
// K3: W_eps[b,h,i,j] (f32, lives in d_out during NS)
__global__ __launch_bounds__(256) void wbuild_kernel(
    const __half* __restrict__ QL, const __half* __restrict__ KL,
    const float* __restrict__ LM, float* __restrict__ W) {
  int bh = blockIdx.y;
  int b = bh >> 3;
  int i0 = blockIdx.x * 64;
  __shared__ float ks[128][65];
  __shared__ float qs[64][65];
  int tid = threadIdx.x;
  const __half* klb = KL + (size_t)bh * (Mm * Dd);
  const __half* qlb = QL + (size_t)bh * (Mm * Dd);
  for (int e = tid; e < 128 * 64; e += 256) ks[e >> 6][e & 63] = h2f(klb[e]);
  for (int e = tid; e < 64 * 64; e += 256) qs[e >> 6][e & 63] = h2f(qlb[i0 * 64 + e]);
  __syncthreads();
  for (int e = tid; e < 64 * 128; e += 256) {
    int il = e >> 7, j = e & 127;
    int i = i0 + il;
    float s = 0.f;
#pragma unroll
    for (int d = 0; d < 64; ++d) s += fabsf(qs[il][d] - ks[j][d]);
    float wv = expf(-s * 0.25f);
    float pr = LM[b * Mm + i] * LM[b * Mm + j];
    float diag = (i == j) ? 1.f : 0.f;
    wv = wv * pr + diag * (1.f - pr) + diag * NS_EPS;
    W[(size_t)bh * (Mm * Mm) + i * 128 + j] = wv;
  }
}

// ---------------------------------------------------------------------------
// K4: X0 = 2/(fro+1e-8) * W^T  (f32)
__global__ __launch_bounds__(256) void nsinit_kernel(const float* __restrict__ W,
                                                     float* __restrict__ X) {
  int bh = blockIdx.x;
  const float* Wb = W + (size_t)bh * 16384;
  float* Xb = X + (size_t)bh * 16384;
  __shared__ float red[256];
  int tid = threadIdx.x;
  float s = 0.f;
  for (int e = tid; e < 16384; e += 256) { float wv = Wb[e]; s += wv * wv; }
  red[tid] = s;
  __syncthreads();
  for (int off = 128; off > 0; off >>= 1) {
    if (tid < off) red[tid] += red[tid + off];
    __syncthreads();
  }
  float scale = 2.f / (sqrtf(red[0]) + 1e-8f);
  for (int e = tid; e < 16384; e += 256) {
    int i = e >> 7, j = e & 127;
    Xb[e] = scale * Wb[j * 128 + i];
  }
}

// ---------------------------------------------------------------------------
// K5: ns_iter — one fused NS iteration: Xn = Xc @ (2I - W @ Xc).
// Block = (column-block cb of 32, bh). Phase 1: T[:,cb] in regs via LDS k-tiles
// of W; phase 2: Xn[:,cb] = Xc @ T[:,cb].
__global__ __launch_bounds__(256) void ns_iter(const float* __restrict__ W,
                                               const float* __restrict__ Xc,
                                               float* __restrict__ Xn) {
  int bh = blockIdx.y;
  int cb = blockIdx.x;  // 0..3
  const float* Wb = W + (size_t)bh * 16384;
  const float* Xb = Xc + (size_t)bh * 16384;
  float* Ob = Xn + (size_t)bh * 16384;
  __shared__ float Xs[128][33];  // Xc[:, cb*32+jc]
  __shared__ float Ts[128][33];  // T[:, jc]
  __shared__ float St[128][33];  // staging k-tile
  int tid = threadIdx.x;
  int jc = tid & 31;
  int ibase = (tid >> 5) * 16;
  for (int e = tid; e < 4096; e += 256) {
    int k = e >> 5, j = e & 31;
    Xs[k][j] = Xb[(size_t)k * 128 + cb * 32 + j];
  }
  float acc[16];
#pragma unroll
  for (int r = 0; r < 16; ++r) acc[r] = 0.f;
  for (int kt = 0; kt < 4; ++kt) {
    __syncthreads();
    for (int e = tid; e < 4096; e += 256) {
      int i = e >> 5, kk = e & 31;
      St[i][kk] = Wb[(size_t)i * 128 + kt * 32 + kk];
    }
    __syncthreads();
#pragma unroll 8
    for (int kk = 0; kk < 32; ++kk) {
      float xv = Xs[kt * 32 + kk][jc];
#pragma unroll
      for (int r = 0; r < 16; ++r) acc[r] += St[ibase + r][kk] * xv;
    }
  }
#pragma unroll
  for (int r = 0; r < 16; ++r) {
    int i = ibase + r;
    Ts[i][jc] = ((i == cb * 32 + jc) ? 2.f : 0.f) - acc[r];
  }
  float acc2[16];
#pragma unroll
  for (int r = 0; r < 16; ++r) acc2[r] = 0.f;
  for (int kt = 0; kt < 4; ++kt) {
    __syncthreads();  // also orders Ts writes before Ts reads
    for (int e = tid; e < 4096; e += 256) {
      int i = e >> 5, kk = e & 31;
      St[i][kk] = Xb[(size_t)i * 128 + kt * 32 + kk];
    }
    __syncthreads();
#pragma unroll 8
    for (int kk = 0; kk < 32; ++kk) {
      float tv = Ts[kt * 32 + kk][jc];
#pragma unroll
      for (int r = 0; r < 16; ++r) acc2[r] += St[ibase + r][kk] * tv;
    }
  }
#pragma unroll
  for (int r = 0; r < 16; ++r)
    Ob[(size_t)(ibase + r) * 128 + cb * 32 + jc] = acc2[r];
}

// ---------------------------------------------------------------------------
// K6: zero KTV
__global__ __launch_bounds__(256) void zero_kernel(float* __restrict__ p, int n) {
  int i = blockIdx.x * 256 + threadIdx.x;
  if (i < n) p[i] = 0.f;
}

// ---------------------------------------------------------------------------
// K7: ktv v3 — fused C_k + K^T V, n-chunk parallel, atomicAdd partials.
__global__ __launch_bounds__(256) void ktv_fused(
    const __half* __restrict__ K, const __half* __restrict__ QL,
    const float* __restrict__ LM, const __half* __restrict__ V,
    float* __restrict__ KTV) {
  int jt = blockIdx.x;   // 0..7 (16 j each)
  int bh = blockIdx.y;   // 16
  int nc = blockIdx.z;   // 0..7 (128 n each)
  int b = bh >> 3, h = bh & 7;
  int j0 = jt * 16;
  __shared__ float qls[16][65];
  __shared__ float Ks[32][65];
  __shared__ float Vs[32][65];
  __shared__ float P[32][17];
  int tid = threadIdx.x;
  for (int e = tid; e < 1024; e += 256)
    qls[e >> 6][e & 63] = h2f(QL[(size_t)bh * 8192 + (size_t)(j0 + (e >> 6)) * 64 + (e & 63)]);
  float acc[4] = {};
  for (int nt = 0; nt < 4; ++nt) {
    int n0 = nc * 128 + nt * 32;
    __syncthreads();
    for (int e = tid; e < 2048; e += 256) {
      int nn = e >> 6, d = e & 63;
      size_t gi = (size_t)b * (Nn * Cc) + (size_t)(n0 + nn) * 512 + h * 64 + d;
      Ks[nn][d] = h2f(K[gi]);
      Vs[nn][d] = h2f(V[gi]);
    }
    __syncthreads();
#pragma unroll
    for (int r = 0; r < 2; ++r) {
      int e = tid + 256 * r;
      int j = e >> 5, n = e & 31;
      float s = 0.f;
#pragma unroll
      for (int d = 0; d < 64; ++d) s += fabsf(Ks[n][d] - qls[j][d]);
      P[n][j] = expf(-s * 0.25f);
    }
    __syncthreads();
    {
      int d = tid & 63;
#pragma unroll
      for (int r = 0; r < 4; ++r) {
        int j = (tid >> 6) + 4 * r;
        float a = 0.f;
#pragma unroll 8
        for (int n = 0; n < 32; ++n) a += P[n][j] * Vs[n][d];
        acc[r] += a;
      }
    }
  }
  {
    int d = tid & 63;
#pragma unroll
    for (int r = 0; r < 4; ++r) {
      int j = (tid >> 6) + 4 * r;
      atomicAdd(&KTV[(size_t)bh * 8192 + (size_t)(j0 + j) * 64 + d],
                acc[r] * LM[b * 128 + j0 + j]);
    }
  }
}

// ---------------------------------------------------------------------------
// K8: CTX[bh,i,d] = sum_j X[bh,i,j] * KTV[bh,j,d]  (f32 in, f16 out)
__global__ __launch_bounds__(256) void ctx_kernel(const float* __restrict__ X,
                                                  const float* __restrict__ KTV,
                                                  __half* __restrict__ CTX) {
  int bh = blockIdx.y;
  int i = blockIdx.x * 4 + (threadIdx.x >> 6);
  int d = threadIdx.x & 63;
  const float* wb = X + (size_t)bh * 16384 + (size_t)i * 128;
  const float* kb = KTV + (size_t)bh * 8192 + d;
  float acc = 0.f;
#pragma unroll 4
  for (int jj = 0; jj < 128; ++jj) acc += wb[jj] * kb[(size_t)jj * 64];
  CTX[(size_t)bh * 8192 + (size_t)i * 64 + d] = f2h(acc);
}

// ---------------------------------------------------------------------------
// K9: stats_partial — computes C_q P-tile, writes it to Pbuf (f16, in d_out),
// and per-j partial sums to PS.
__global__ __launch_bounds__(256) void stats_partial(
    const __half* __restrict__ Q, const __half* __restrict__ KL,
    const float* __restrict__ LM, const float* __restrict__ tm,
    float* __restrict__ PS, __half* __restrict__ Pbuf) {
  int nt = blockIdx.x;
  int bh = blockIdx.y;
  int b = bh >> 3, h = bh & 7;
  int n0 = nt * 16;
  __shared__ float kls[128][65];
  __shared__ float qs[16][65];
  __shared__ float part[256][3];
  int tid = threadIdx.x;
  for (int e = tid; e < 8192; e += 256) kls[e >> 6][e & 63] = h2f(KL[(size_t)bh * 8192 + e]);
  for (int e = tid; e < 1024; e += 256)
    qs[e >> 6][e & 63] =
        h2f(Q[(size_t)b * (Nn * Cc) + (size_t)(n0 + (e >> 6)) * 512 + h * 64 + (e & 63)]);
  __syncthreads();
  int j = tid & 127, nb = tid >> 7;
  float lmj = LM[b * 128 + j];
  float s1 = 0.f, s2 = 0.f, s3 = 0.f;
#pragma unroll
  for (int r = 0; r < 8; ++r) {
    int nn = nb * 8 + r;
    float s = 0.f;
#pragma unroll
    for (int d = 0; d < 64; ++d) s += fabsf(qs[nn][d] - kls[j][d]);
    float xv = expf(-s * 0.25f) * lmj;
    Pbuf[((size_t)bh * 1024 + n0 + nn) * 128 + j] = f2h(xv);
    float t = tm[b * 1024 + n0 + nn];
    float xt = xv * t;
    s1 += xt; s2 += xt * xt; s3 += xt * t;
  }
  part[tid][0] = s1; part[tid][1] = s2; part[tid][2] = s3;
  __syncthreads();
  if (tid < 128) {
    float a = part[tid][0] + part[tid + 128][0];
    float c = part[tid][1] + part[tid + 128][1];
    float e = part[tid][2] + part[tid + 128][2];
    size_t base = ((size_t)(b * 64 + nt) * 8 + h) * 384 + tid * 3;
    PS[base] = a; PS[base + 1] = c; PS[base + 2] = e;
  }
}

// ---------------------------------------------------------------------------
// K10: stats_final — reduce PS over 128 (b,nt) tiles per (h,j).
__global__ __launch_bounds__(256) void stats_final(const float* __restrict__ PS,
                                                   const float* __restrict__ tm,
                                                   float* __restrict__ MU,
                                                   float* __restrict__ RS) {
  __shared__ float red[256][2];
  __shared__ float ts0, ts1;
  int tid = threadIdx.x;
  float a = 0.f, c = 0.f;
  for (int i = tid; i < 2048; i += 256) { float t = tm[i]; a += t; c += t * t; }
  red[tid][0] = a; red[tid][1] = c;
  __syncthreads();
  for (int off = 128; off > 0; off >>= 1) {
    if (tid < off) { red[tid][0] += red[tid + off][0]; red[tid][1] += red[tid + off][1]; }
    __syncthreads();
  }
  if (tid == 0) { ts0 = red[0][0]; ts1 = red[0][1]; }
  __syncthreads();
  int hj = blockIdx.x * 256 + tid;
  int h = hj >> 7, j = hj & 127;
  float s1 = 0.f, s2 = 0.f, s3 = 0.f;
  for (int bnt = 0; bnt < 128; ++bnt) {
    const float* p = PS + ((size_t)bnt * 8 + h) * 384 + j * 3;
    s1 += p[0]; s2 += p[1]; s3 += p[2];
  }
  float valid = fmaxf(ts0, 1.f);
  float mu = s1 / valid;
  float var = (s2 - 2.f * mu * s3 + mu * mu * ts1) / valid;
  var = fmaxf(var, 0.f);
  MU[hj] = mu;
  RS[hj] = rsqrtf(var + WHITE_EPS);
}

// ---------------------------------------------------------------------------
// K11: scrambled depthwise conv -> VL f16 (in d_ws)
__global__ __launch_bounds__(256) void vlocal_kernel(
    const __half* __restrict__ V, const float* __restrict__ dwc_w,
    const float* __restrict__ dwc_b, const float* __restrict__ tm,
    __half* __restrict__ VL) {
  int idx = blockIdx.x * 256 + threadIdx.x;
  if (idx >= Bz * Nn * Cc) return;
  int c = idx & 511;
  int t = (idx >> 9) & 1023;
  int b = idx >> 19;
  float acc = dwc_b[c];
#pragma unroll
  for (int k = 0; k < 3; ++k) {
    int u = t - 1 + k;
    if (u >= 0 && u < 1024) {
      int n = 2 * c + (u >> 9);
      int ch = u & 511;
      acc += dwc_w[c * 3 + k] * h2f(V[(size_t)b * (Nn * Cc) + (size_t)n * 512 + ch]);
    }
  }
  VL[idx] = f2h(acc * tm[b * 1024 + t]);
}

// ---------------------------------------------------------------------------
// K12: ga v3 — load precomputed P, whiten, @context, accumulate into VL.
__global__ __launch_bounds__(256) void ga_fused(
    const __half* __restrict__ Pbuf, const float* __restrict__ MU,
    const float* __restrict__ RS, const __half* __restrict__ CTXg,
    const float* __restrict__ tm, __half* __restrict__ VL) {
  int bh = blockIdx.y;
  int b = bh >> 3, h = bh & 7;
  int n0 = blockIdx.x * 16;
  __shared__ __half Ps[16][130];
  __shared__ __half2 ctx2[128][32];
  __shared__ float musr[128][2];
  int tid = threadIdx.x;
  for (int e = tid; e < 2048; e += 256)
    Ps[e >> 7][e & 127] = Pbuf[((size_t)bh * 1024 + n0 + (e >> 7)) * 128 + (e & 127)];
  {
    const __half2* cg = (const __half2*)(CTXg + (size_t)bh * 8192);
    for (int e = tid; e < 4096; e += 256) ctx2[e >> 5][e & 31] = cg[e];
  }
  if (tid < 128) { musr[tid][0] = MU[h * 128 + tid]; musr[tid][1] = RS[h * 128 + tid]; }
  __syncthreads();
  int nn = tid >> 4, dq = tid & 15;
  float a0 = 0.f, a1 = 0.f, a2 = 0.f, a3 = 0.f;
#pragma unroll 4
  for (int j = 0; j < 128; ++j) {
    float pj = (h2f(Ps[nn][j]) - musr[j][0]) * musr[j][1];
    __half2 c01 = ctx2[j][dq * 2];
    __half2 c23 = ctx2[j][dq * 2 + 1];
    a0 += pj * h2f(c01.x); a1 += pj * h2f(c01.y);
    a2 += pj * h2f(c23.x); a3 += pj * h2f(c23.y);
  }
  float t = tm[b * 1024 + n0 + nn];
  float t2 = t * t;
  size_t base = (size_t)b * (Nn * Cc) + (size_t)(n0 + nn) * 512 + h * 64 + dq * 4;
  VL[base] = f2h(h2f(VL[base]) + t2 * a0);
  VL[base + 1] = f2h(h2f(VL[base + 1]) + t2 * a1);
  VL[base + 2] = f2h(h2f(VL[base + 2]) + t2 * a2);
  VL[base + 3] = f2h(h2f(VL[base + 3]) + t2 * a3);
}

// ---------------------------------------------------------------------------
// K13: projection: out = (VL @ proj_w.T + proj_b) * tm, f32 store.
__global__ __launch_bounds__(256) void proj_gemm(
    const __half* __restrict__ Ain, const float* __restrict__ w,
    const float* __restrict__ bias, const float* __restrict__ tm,
    float* __restrict__ out) {
  __shared__ float As[64][33];
  __shared__ float Bs[64][33];
  int m0 = blockIdx.x * 64;
  int n0 = blockIdx.y * 64;
  int tid = threadIdx.x;
  int ty = tid >> 4, tx = tid & 15;
  float acc[4][4] = {};
  for (int k0 = 0; k0 < 512; k0 += 32) {
    int r = tid >> 2;
    int kk = (tid & 3) * 8;
    const __half* srcA = Ain + (size_t)(m0 + r) * 512 + k0 + kk;
    const float* srcB = w + (size_t)(n0 + r) * 512 + k0 + kk;
#pragma unroll
    for (int u = 0; u < 8; ++u) As[r][kk + u] = h2f(srcA[u]);
#pragma unroll
    for (int u = 0; u < 8; ++u) Bs[r][kk + u] = srcB[u];
    __syncthreads();
#pragma unroll
    for (int q = 0; q < 32; ++q) {
      float a[4], b[4];
#pragma unroll
      for (int i = 0; i < 4; ++i) a[i] = As[ty * 4 + i][q];
#pragma unroll
      for (int j = 0; j < 4; ++j) b[j] = Bs[tx * 4 + j][q];
#pragma unroll
      for (int i = 0; i < 4; ++i)
#pragma unroll
        for (int j = 0; j < 4; ++j) acc[i][j] += a[i] * b[j];
    }
    __syncthreads();
  }
#pragma unroll
  for (int i = 0; i < 4; ++i) {
    int row = m0 + ty * 4 + i;
    int b_ = row >> 10, n_ = row & 1023;
    float t = tm[b_ * 1024 + n_];
#pragma unroll
    for (int j = 0; j < 4; ++j) {
      int co = n0 + tx * 4 + j;
      out[(size_t)row * 512 + co] = (acc[i][j] + bias[co]) * t;
    }
  }
}

// ---------------------------------------------------------------------------
// d_ws: 11.26 MiB high-water (proven safe). PS overlays dead XA/XB after ctx.
// d_out (4 MiB): W f32 (NS) -> Pbuf f16 (stats->ga) -> final f32 output.
extern "C" void kernel_launch(void* const* d_in, const int* in_sizes, int n_in,
                              void* d_out, int out_size, void* d_ws, size_t ws_size,
                              hipStream_t stream) {
  const float* x      = (const float*)d_in[0];
  const float* tm     = (const float*)d_in[1];
  const float* qkv_w  = (const float*)d_in[2];
  const float* qkv_b  = (const float*)d_in[3];
  const float* proj_w = (const float*)d_in[4];
  const float* proj_b = (const float*)d_in[5];
  const float* dwc_w  = (const float*)d_in[6];
  const float* dwc_b  = (const float*)d_in[7];
  float* out = (float*)d_out;

  char* wsb = (char*)d_ws;
  __half* Qh  = (__half*)(wsb + 0);          // 2 MiB
  __half* Kh  = (__half*)(wsb + 2097152);    // 2 MiB
  __half* Vh  = (__half*)(wsb + 4194304);    // 2 MiB
  __half* VLh = (__half*)(wsb + 6291456);    // 2 MiB
  __half* QLh = (__half*)(wsb + 8388608);    // 256 KiB
  __half* KLh = (__half*)(wsb + 8650752);    // 256 KiB
  float*  LM  = (float*)(wsb + 8912896);     // 1 KiB
  float*  MU  = (float*)(wsb + 8913920);     // 4 KiB
  float*  RS  = (float*)(wsb + 8918016);     // 4 KiB
  float*  KTV = (float*)(wsb + 8922112);     // 512 KiB
  __half* CTX = (__half*)(wsb + 9446400);    // 256 KiB
  float*  XA  = (float*)(wsb + 9708544);     // 1 MiB
  float*  XB  = (float*)(wsb + 10757120);    // 1 MiB (end 11,805,696)
  float*  PS  = (float*)(wsb + 9708544);     // 1.5 MiB (overlays XA+XB after ctx)

  char* ob = (char*)d_out;
  float*  Wf   = (float*)ob;      // 1 MiB, alive through NS
  __half* Pbuf = (__half*)ob;     // 4 MiB, alive stats_partial -> ga_fused

  qkv_gemm<<<dim3(32, 24), 256, 0, stream>>>(x, qkv_w, qkv_b, tm, Qh, Kh, Vh);
  pool_kernel<<<dim3(16, 16), 256, 0, stream>>>(Qh, Kh, tm, QLh, KLh, LM);
  wbuild_kernel<<<dim3(2, 16), 256, 0, stream>>>(QLh, KLh, LM, Wf);
  nsinit_kernel<<<16, 256, 0, stream>>>(Wf, XA);
  float* Xc = XA;
  float* Xn = XB;
  for (int it = 0; it < 5; ++it) {
    ns_iter<<<dim3(4, 16), 256, 0, stream>>>(Wf, Xc, Xn);
    float* tswap = Xc; Xc = Xn; Xn = tswap;
  }
  zero_kernel<<<512, 256, 0, stream>>>(KTV, 131072);
  ktv_fused<<<dim3(8, 16, 8), 256, 0, stream>>>(Kh, QLh, LM, Vh, KTV);
  ctx_kernel<<<dim3(32, 16), 256, 0, stream>>>(Xc, KTV, CTX);
  // XA/XB and Wf now dead -> PS (ws) and Pbuf (d_out) regions free
  stats_partial<<<dim3(64, 16), 256, 0, stream>>>(Qh, KLh, LM, tm, PS, Pbuf);
  stats_final<<<4, 256, 0, stream>>>(PS, tm, MU, RS);
  vlocal_kernel<<<4096, 256, 0, stream>>>(Vh, dwc_w, dwc_b, tm, VLh);
  ga_fused<<<dim3(64, 16), 256, 0, stream>>>(Pbuf, MU, RS, CTX, tm, VLh);
  proj_gemm<<<dim3(32, 8), 256, 0, stream>>>(VLh, proj_w, proj_b, tm, out);
}

// Round 8
// 471.003 us; speedup vs baseline: 2.9860x; 1.2615x over previous
//
#include <hip/hip_runtime.h>
#include <hip/hip_bf16.h>
#include <hip/hip_fp16.h>

// B=2, N=1024, C=512, H=8, D=64, m=128, p=8
#define Hh 8
#define Bz 2
#define Nn 1024
#define Cc 512
#define Dd 64
#define Mm 128
#define NS_EPS 1e-4f
#define WHITE_EPS 1e-5f

__device__ __forceinline__ float h2f(__half v) { return __half2float(v); }
__device__ __forceinline__ __half f2h(float v) { return __float2half(v); }

typedef _Float16 half8 __attribute__((ext_vector_type(8)));
typedef float float4v __attribute__((ext_vector_type(4)));

// ---------------------------------------------------------------------------
// K1: QKV GEMM via MFMA f16. M=2048, N=1536, K=512. Block tile 128x128,
// 4 waves in 2x2 (each 64x64 = 4x4 MFMA 16x16x32 tiles). Staging converts
// f32 global -> f16 LDS in-flight. LDS rows padded to 40 f16 (bank-safe).
__global__ __launch_bounds__(256) void qkv_gemm(
    const float* __restrict__ x, const float* __restrict__ w,
    const float* __restrict__ bias, const float* __restrict__ tm,
    __half* __restrict__ Q, __half* __restrict__ K, __half* __restrict__ V) {
  __shared__ _Float16 As[128 * 40];
  __shared__ _Float16 Bs[128 * 40];
  int m0 = blockIdx.x * 128, n0 = blockIdx.y * 128;
  int tid = threadIdx.x;
  int lane = tid & 63, wv = tid >> 6;
  int wm = (wv >> 1) * 64, wn = (wv & 1) * 64;
  int l15 = lane & 15, quad = lane >> 4;
  int srow = tid >> 1, shalf = tid & 1;
  float4v acc[4][4] = {};
  for (int k0 = 0; k0 < 512; k0 += 32) {
    __syncthreads();
    {
      const float4* ga = (const float4*)(x + (size_t)(m0 + srow) * 512 + k0 + shalf * 16);
      const float4* gb = (const float4*)(w + (size_t)(n0 + srow) * 512 + k0 + shalf * 16);
      float4 a0 = ga[0], a1 = ga[1], a2 = ga[2], a3 = ga[3];
      float4 b0 = gb[0], b1 = gb[1], b2 = gb[2], b3 = gb[3];
      half8 ha0 = {(_Float16)a0.x, (_Float16)a0.y, (_Float16)a0.z, (_Float16)a0.w,
                   (_Float16)a1.x, (_Float16)a1.y, (_Float16)a1.z, (_Float16)a1.w};
      half8 ha1 = {(_Float16)a2.x, (_Float16)a2.y, (_Float16)a2.z, (_Float16)a2.w,
                   (_Float16)a3.x, (_Float16)a3.y, (_Float16)a3.z, (_Float16)a3.w};
      half8 hb0 = {(_Float16)b0.x, (_Float16)b0.y, (_Float16)b0.z, (_Float16)b0.w,
                   (_Float16)b1.x, (_Float16)b1.y, (_Float16)b1.z, (_Float16)b1.w};
      half8 hb1 = {(_Float16)b2.x, (_Float16)b2.y, (_Float16)b2.z, (_Float16)b2.w,
                   (_Float16)b3.x, (_Float16)b3.y, (_Float16)b3.z, (_Float16)b3.w};
      int lo = srow * 40 + shalf * 16;
      *(half8*)&As[lo] = ha0;
      *(half8*)&As[lo + 8] = ha1;
      *(half8*)&Bs[lo] = hb0;
      *(half8*)&Bs[lo + 8] = hb1;
    }
    __syncthreads();
    half8 a[4], b[4];
#pragma unroll
    for (int mt = 0; mt < 4; ++mt)
      a[mt] = *(const half8*)&As[(wm + mt * 16 + l15) * 40 + quad * 8];
#pragma unroll
    for (int nt = 0; nt < 4; ++nt)
      b[nt] = *(const half8*)&Bs[(wn + nt * 16 + l15) * 40 + quad * 8];
#pragma unroll
    for (int mt = 0; mt < 4; ++mt)
#pragma unroll
      for (int nt = 0; nt < 4; ++nt)
        acc[mt][nt] =
            __builtin_amdgcn_mfma_f32_16x16x32_f16(a[mt], b[nt], acc[mt][nt], 0, 0, 0);
  }
#pragma unroll
  for (int mt = 0; mt < 4; ++mt) {
#pragma unroll
    for (int r = 0; r < 4; ++r) {
      int row = m0 + wm + mt * 16 + quad * 4 + r;
      int b_ = row >> 10, n_ = row & 1023;
      float t = tm[b_ * 1024 + n_];
#pragma unroll
      for (int nt = 0; nt < 4; ++nt) {
        int c3 = n0 + wn + nt * 16 + l15;
        float v = (acc[mt][nt][r] + bias[c3]) * t;
        int sec = c3 >> 9, ch = c3 & 511;
        __half* dst = (sec == 0) ? Q : (sec == 1 ? K : V);
        dst[(size_t)b_ * (Nn * Cc) + (size_t)n_ * 512 + ch] = f2h(v);
      }
    }
  }
}

// ---------------------------------------------------------------------------
// K2: pool — block per (b,h,u-tile of 64). Coalesced row staging.
__global__ __launch_bounds__(256) void pool_kernel(
    const __half* __restrict__ Q, const __half* __restrict__ K,
    const float* __restrict__ tm, __half* __restrict__ QL,
    __half* __restrict__ KL, float* __restrict__ LM) {
  int ut = blockIdx.x;
  int bh = blockIdx.y;
  int b = bh >> 3, h = bh & 7;
  int u0 = ut * 64;
  int delta = u0 >> 9;
  int ch0 = u0 & 511;
  __shared__ float Qs[64][65];
  __shared__ float Ks[64][65];
  int tid = threadIdx.x;
  for (int e = tid; e < 4096; e += 256) {
    int d = e >> 6, uu = e & 63;
    int row = 2 * (h * 64 + d) + delta;
    size_t gi = (size_t)b * (Nn * Cc) + (size_t)row * 512 + ch0 + uu;
    Qs[d][uu] = h2f(Q[gi]);
    Ks[d][uu] = h2f(K[gi]);
  }
  __syncthreads();
  int d = tid & 63, s = tid >> 6;
#pragma unroll
  for (int jr = 0; jr < 2; ++jr) {
    int jl = s + 4 * jr;
    int j = ut * 8 + jl;
    float pm = 0.f, sq = 0.f, sk = 0.f;
#pragma unroll
    for (int i = 0; i < 8; ++i) {
      float t = tm[b * 1024 + 8 * j + i];
      pm += t;
      sq += Qs[d][8 * jl + i] * t;
      sk += Ks[d][8 * jl + i] * t;
    }
    pm *= 0.125f;
    float pms = fmaxf(pm, 1e-6f);
    size_t oi = ((size_t)bh * 128 + j) * 64 + d;
    QL[oi] = f2h(sq * 0.125f / pms);
    KL[oi] = f2h(sk * 0.125f / pms);
    if (h == 0 && d == 0) LM[b * 128 + j] = (pm > 0.f) ? 1.f : 0.f;
  }
}

// ---------------------------------------------------------------------------
// K3: W_eps[b,h,i,j] (f32, lives in d_out during NS)
__global__ __launch_bounds__(256) void wbuild_kernel(
    const __half* __restrict__ QL, const __half* __restrict__ KL,
    const float* __restrict__ LM, float* __restrict__ W) {
  int bh = blockIdx.y;
  int b = bh >> 3;
  int i0 = blockIdx.x * 64;
  __shared__ float ks[128][65];
  __shared__ float qs[64][65];
  int tid = threadIdx.x;
  const __half* klb = KL + (size_t)bh * (Mm * Dd);
  const __half* qlb = QL + (size_t)bh * (Mm * Dd);
  for (int e = tid; e < 128 * 64; e += 256) ks[e >> 6][e & 63] = h2f(klb[e]);
  for (int e = tid; e < 64 * 64; e += 256) qs[e >> 6][e & 63] = h2f(qlb[i0 * 64 + e]);
  __syncthreads();
  for (int e = tid; e < 64 * 128; e += 256) {
    int il = e >> 7, j = e & 127;
    int i = i0 + il;
    float s = 0.f;
#pragma unroll
    for (int d = 0; d < 64; ++d) s += fabsf(qs[il][d] - ks[j][d]);
    float wv = expf(-s * 0.25f);
    float pr = LM[b * Mm + i] * LM[b * Mm + j];
    float diag = (i == j) ? 1.f : 0.f;
    wv = wv * pr + diag * (1.f - pr) + diag * NS_EPS;
    W[(size_t)bh * (Mm * Mm) + i * 128 + j] = wv;
  }
}

// ---------------------------------------------------------------------------
// K4: X0 = 2/(fro+1e-8) * W^T  (f32)
__global__ __launch_bounds__(256) void nsinit_kernel(const float* __restrict__ W,
                                                     float* __restrict__ X) {
  int bh = blockIdx.x;
  const float* Wb = W + (size_t)bh * 16384;
  float* Xb = X + (size_t)bh * 16384;
  __shared__ float red[256];
  int tid = threadIdx.x;
  float s = 0.f;
  for (int e = tid; e < 16384; e += 256) { float wv = Wb[e]; s += wv * wv; }
  red[tid] = s;
  __syncthreads();
  for (int off = 128; off > 0; off >>= 1) {
    if (tid < off) red[tid] += red[tid + off];
    __syncthreads();
  }
  float scale = 2.f / (sqrtf(red[0]) + 1e-8f);
  for (int e = tid; e < 16384; e += 256) {
    int i = e >> 7, j = e & 127;
    Xb[e] = scale * Wb[j * 128 + i];
  }
}

// ---------------------------------------------------------------------------
// K5: ns_iter v2 — Xn = Xc @ (2I - W @ Xc), 8 column-blocks of 16.
__global__ __launch_bounds__(256) void ns_iter(const float* __restrict__ W,
                                               const float* __restrict__ Xc,
                                               float* __restrict__ Xn) {
  int bh = blockIdx.y;
  int cb = blockIdx.x;  // 0..7
  const float* Wb = W + (size_t)bh * 16384;
  const float* Xb = Xc + (size_t)bh * 16384;
  float* Ob = Xn + (size_t)bh * 16384;
  __shared__ float Xs[128][17];
  __shared__ float Ts[128][17];
  __shared__ float St[128][33];
  int tid = threadIdx.x;
  int jc = tid & 15;
  int ibase = (tid >> 4) * 8;
  for (int e = tid; e < 2048; e += 256) {
    int k = e >> 4, j = e & 15;
    Xs[k][j] = Xb[(size_t)k * 128 + cb * 16 + j];
  }
  float acc[8];
#pragma unroll
  for (int r = 0; r < 8; ++r) acc[r] = 0.f;
  for (int kt = 0; kt < 4; ++kt) {
    __syncthreads();
    for (int e = tid; e < 4096; e += 256)
      St[e >> 5][e & 31] = Wb[(size_t)(e >> 5) * 128 + kt * 32 + (e & 31)];
    __syncthreads();
#pragma unroll 8
    for (int kk = 0; kk < 32; ++kk) {
      float xv = Xs[kt * 32 + kk][jc];
#pragma unroll
      for (int r = 0; r < 8; ++r) acc[r] += St[ibase + r][kk] * xv;
    }
  }
#pragma unroll
  for (int r = 0; r < 8; ++r) {
    int i = ibase + r;
    Ts[i][jc] = ((i == cb * 16 + jc) ? 2.f : 0.f) - acc[r];
  }
  float acc2[8];
#pragma unroll
  for (int r = 0; r < 8; ++r) acc2[r] = 0.f;
  for (int kt = 0; kt < 4; ++kt) {
    __syncthreads();  // orders Ts writes before St overwrite + reads
    for (int e = tid; e < 4096; e += 256)
      St[e >> 5][e & 31] = Xb[(size_t)(e >> 5) * 128 + kt * 32 + (e & 31)];
    __syncthreads();
#pragma unroll 8
    for (int kk = 0; kk < 32; ++kk) {
      float tv = Ts[kt * 32 + kk][jc];
#pragma unroll
      for (int r = 0; r < 8; ++r) acc2[r] += St[ibase + r][kk] * tv;
    }
  }
#pragma unroll
  for (int r = 0; r < 8; ++r)
    Ob[(size_t)(ibase + r) * 128 + cb * 16 + jc] = acc2[r];
}

// ---------------------------------------------------------------------------
// K6: zero KTV
__global__ __launch_bounds__(256) void zero_kernel(float* __restrict__ p, int n) {
  int i = blockIdx.x * 256 + threadIdx.x;
  if (i < n) p[i] = 0.f;
}

// ---------------------------------------------------------------------------
// K7: ktv — fused C_k + K^T V, n-chunk parallel, atomicAdd partials.
__global__ __launch_bounds__(256) void ktv_fused(
    const __half* __restrict__ K, const __half* __restrict__ QL,
    const float* __restrict__ LM, const __half* __restrict__ V,
    float* __restrict__ KTV) {
  int jt = blockIdx.x;
  int bh = blockIdx.y;
  int nc = blockIdx.z;
  int b = bh >> 3, h = bh & 7;
  int j0 = jt * 16;
  __shared__ float qls[16][65];
  __shared__ float Ks[32][65];
  __shared__ float Vs[32][65];
  __shared__ float P[32][17];
  int tid = threadIdx.x;
  for (int e = tid; e < 1024; e += 256)
    qls[e >> 6][e & 63] = h2f(QL[(size_t)bh * 8192 + (size_t)(j0 + (e >> 6)) * 64 + (e & 63)]);
  float acc[4] = {};
  for (int nt = 0; nt < 4; ++nt) {
    int n0 = nc * 128 + nt * 32;
    __syncthreads();
    for (int e = tid; e < 2048; e += 256) {
      int nn = e >> 6, d = e & 63;
      size_t gi = (size_t)b * (Nn * Cc) + (size_t)(n0 + nn) * 512 + h * 64 + d;
      Ks[nn][d] = h2f(K[gi]);
      Vs[nn][d] = h2f(V[gi]);
    }
    __syncthreads();
#pragma unroll
    for (int r = 0; r < 2; ++r) {
      int e = tid + 256 * r;
      int j = e >> 5, n = e & 31;
      float s = 0.f;
#pragma unroll
      for (int d = 0; d < 64; ++d) s += fabsf(Ks[n][d] - qls[j][d]);
      P[n][j] = expf(-s * 0.25f);
    }
    __syncthreads();
    {
      int d = tid & 63;
#pragma unroll
      for (int r = 0; r < 4; ++r) {
        int j = (tid >> 6) + 4 * r;
        float a = 0.f;
#pragma unroll 8
        for (int n = 0; n < 32; ++n) a += P[n][j] * Vs[n][d];
        acc[r] += a;
      }
    }
  }
  {
    int d = tid & 63;
#pragma unroll
    for (int r = 0; r < 4; ++r) {
      int j = (tid >> 6) + 4 * r;
      atomicAdd(&KTV[(size_t)bh * 8192 + (size_t)(j0 + j) * 64 + d],
                acc[r] * LM[b * 128 + j0 + j]);
    }
  }
}

// ---------------------------------------------------------------------------
// K8: CTX[bh,i,d] = sum_j X[bh,i,j] * KTV[bh,j,d]  (f32 in, f16 out)
__global__ __launch_bounds__(256) void ctx_kernel(const float* __restrict__ X,
                                                  const float* __restrict__ KTV,
                                                  __half* __restrict__ CTX) {
  int bh = blockIdx.y;
  int i = blockIdx.x * 4 + (threadIdx.x >> 6);
  int d = threadIdx.x & 63;
  const float* wb = X + (size_t)bh * 16384 + (size_t)i * 128;
  const float* kb = KTV + (size_t)bh * 8192 + d;
  float acc = 0.f;
#pragma unroll 4
  for (int jj = 0; jj < 128; ++jj) acc += wb[jj] * kb[(size_t)jj * 64];
  CTX[(size_t)bh * 8192 + (size_t)i * 64 + d] = f2h(acc);
}

// ---------------------------------------------------------------------------
// K9: stats_partial — computes C_q P-tile, stores to Pbuf (f16, d_out) + partials.
__global__ __launch_bounds__(256) void stats_partial(
    const __half* __restrict__ Q, const __half* __restrict__ KL,
    const float* __restrict__ LM, const float* __restrict__ tm,
    float* __restrict__ PS, __half* __restrict__ Pbuf) {
  int nt = blockIdx.x;
  int bh = blockIdx.y;
  int b = bh >> 3, h = bh & 7;
  int n0 = nt * 16;
  __shared__ float kls[128][65];
  __shared__ float qs[16][65];
  __shared__ float part[256][3];
  int tid = threadIdx.x;
  for (int e = tid; e < 8192; e += 256) kls[e >> 6][e & 63] = h2f(KL[(size_t)bh * 8192 + e]);
  for (int e = tid; e < 1024; e += 256)
    qs[e >> 6][e & 63] =
        h2f(Q[(size_t)b * (Nn * Cc) + (size_t)(n0 + (e >> 6)) * 512 + h * 64 + (e & 63)]);
  __syncthreads();
  int j = tid & 127, nb = tid >> 7;
  float lmj = LM[b * 128 + j];
  float s1 = 0.f, s2 = 0.f, s3 = 0.f;
#pragma unroll
  for (int r = 0; r < 8; ++r) {
    int nn = nb * 8 + r;
    float s = 0.f;
#pragma unroll
    for (int d = 0; d < 64; ++d) s += fabsf(qs[nn][d] - kls[j][d]);
    float xv = expf(-s * 0.25f) * lmj;
    Pbuf[((size_t)bh * 1024 + n0 + nn) * 128 + j] = f2h(xv);
    float t = tm[b * 1024 + n0 + nn];
    float xt = xv * t;
    s1 += xt; s2 += xt * xt; s3 += xt * t;
  }
  part[tid][0] = s1; part[tid][1] = s2; part[tid][2] = s3;
  __syncthreads();
  if (tid < 128) {
    float a = part[tid][0] + part[tid + 128][0];
    float c = part[tid][1] + part[tid + 128][1];
    float e = part[tid][2] + part[tid + 128][2];
    size_t base = ((size_t)(b * 64 + nt) * 8 + h) * 384 + tid * 3;
    PS[base] = a; PS[base + 1] = c; PS[base + 2] = e;
  }
}

// ---------------------------------------------------------------------------
// K10: stats_final — reduce PS over 128 (b,nt) tiles per (h,j).
__global__ __launch_bounds__(256) void stats_final(const float* __restrict__ PS,
                                                   const float* __restrict__ tm,
                                                   float* __restrict__ MU,
                                                   float* __restrict__ RS) {
  __shared__ float red[256][2];
  __shared__ float ts0, ts1;
  int tid = threadIdx.x;
  float a = 0.f, c = 0.f;
  for (int i = tid; i < 2048; i += 256) { float t = tm[i]; a += t; c += t * t; }
  red[tid][0] = a; red[tid][1] = c;
  __syncthreads();
  for (int off = 128; off > 0; off >>= 1) {
    if (tid < off) { red[tid][0] += red[tid + off][0]; red[tid][1] += red[tid + off][1]; }
    __syncthreads();
  }
  if (tid == 0) { ts0 = red[0][0]; ts1 = red[0][1]; }
  __syncthreads();
  int hj = blockIdx.x * 256 + tid;
  int h = hj >> 7, j = hj & 127;
  float s1 = 0.f, s2 = 0.f, s3 = 0.f;
  for (int bnt = 0; bnt < 128; ++bnt) {
    const float* p = PS + ((size_t)bnt * 8 + h) * 384 + j * 3;
    s1 += p[0]; s2 += p[1]; s3 += p[2];
  }
  float valid = fmaxf(ts0, 1.f);
  float mu = s1 / valid;
  float var = (s2 - 2.f * mu * s3 + mu * mu * ts1) / valid;
  var = fmaxf(var, 0.f);
  MU[hj] = mu;
  RS[hj] = rsqrtf(var + WHITE_EPS);
}

// ---------------------------------------------------------------------------
// K11: vlocal v2 — LDS-tiled scrambled depthwise conv.
// V[b,n,ch] = v_sp[b, n>>1, (n&1)*512+ch]  (exact inverse of the scramble)
__global__ __launch_bounds__(256) void vlocal_kernel(
    const __half* __restrict__ V, const float* __restrict__ dwc_w,
    const float* __restrict__ dwc_b, const float* __restrict__ tm,
    __half* __restrict__ VL) {
  int t0 = blockIdx.x * 64;
  int ct = blockIdx.y & 7, b = blockIdx.y >> 3;
  int c0 = ct * 64;
  __shared__ float vs[64][67];
  int tid = threadIdx.x;
  for (int e = tid; e < 64 * 66; e += 256) {
    int cl = e / 66, uu = e % 66;
    int u = t0 - 1 + uu;
    float val = 0.f;
    if (u >= 0 && u < 1024) {
      int c = c0 + cl;
      int n = 2 * c + (u >> 9), ch = u & 511;
      val = h2f(V[(size_t)b * (Nn * Cc) + (size_t)n * 512 + ch]);
    }
    vs[cl][uu] = val;
  }
  __syncthreads();
  int cl = tid & 63;
  int c = c0 + cl;
  float w0 = dwc_w[c * 3], w1 = dwc_w[c * 3 + 1], w2 = dwc_w[c * 3 + 2];
  float bb = dwc_b[c];
  int tg = tid >> 6;
#pragma unroll
  for (int i = 0; i < 16; ++i) {
    int tl = tg * 16 + i;
    int t = t0 + tl;
    float acc = bb + w0 * vs[cl][tl] + w1 * vs[cl][tl + 1] + w2 * vs[cl][tl + 2];
    VL[(size_t)b * (Nn * Cc) + (size_t)t * 512 + c] = f2h(acc * tm[b * 1024 + t]);
  }
}

// ---------------------------------------------------------------------------
// K12: ga — load precomputed P, whiten, @context, accumulate into VL.
__global__ __launch_bounds__(256) void ga_fused(
    const __half* __restrict__ Pbuf, const float* __restrict__ MU,
    const float* __restrict__ RS, const __half* __restrict__ CTXg,
    const float* __restrict__ tm, __half* __restrict__ VL) {
  int bh = blockIdx.y;
  int b = bh >> 3, h = bh & 7;
  int n0 = blockIdx.x * 16;
  __shared__ __half Ps[16][130];
  __shared__ __half2 ctx2[128][32];
  __shared__ float musr[128][2];
  int tid = threadIdx.x;
  for (int e = tid; e < 2048; e += 256)
    Ps[e >> 7][e & 127] = Pbuf[((size_t)bh * 1024 + n0 + (e >> 7)) * 128 + (e & 127)];
  {
    const __half2* cg = (const __half2*)(CTXg + (size_t)bh * 8192);
    for (int e = tid; e < 4096; e += 256) ctx2[e >> 5][e & 31] = cg[e];
  }
  if (tid < 128) { musr[tid][0] = MU[h * 128 + tid]; musr[tid][1] = RS[h * 128 + tid]; }
  __syncthreads();
  int nn = tid >> 4, dq = tid & 15;
  float a0 = 0.f, a1 = 0.f, a2 = 0.f, a3 = 0.f;
#pragma unroll 4
  for (int j = 0; j < 128; ++j) {
    float pj = (h2f(Ps[nn][j]) - musr[j][0]) * musr[j][1];
    __half2 c01 = ctx2[j][dq * 2];
    __half2 c23 = ctx2[j][dq * 2 + 1];
    a0 += pj * h2f(c01.x); a1 += pj * h2f(c01.y);
    a2 += pj * h2f(c23.x); a3 += pj * h2f(c23.y);
  }
  float t = tm[b * 1024 + n0 + nn];
  float t2 = t * t;
  size_t base = (size_t)b * (Nn * Cc) + (size_t)(n0 + nn) * 512 + h * 64 + dq * 4;
  VL[base] = f2h(h2f(VL[base]) + t2 * a0);
  VL[base + 1] = f2h(h2f(VL[base + 1]) + t2 * a1);
  VL[base + 2] = f2h(h2f(VL[base + 2]) + t2 * a2);
  VL[base + 3] = f2h(h2f(VL[base + 3]) + t2 * a3);
}

// ---------------------------------------------------------------------------
// K13: proj via MFMA f16. M=2048, N=512, K=512. A=VLh f16, B=proj_w f32->f16.
__global__ __launch_bounds__(256) void proj_gemm(
    const __half* __restrict__ Ain, const float* __restrict__ w,
    const float* __restrict__ bias, const float* __restrict__ tm,
    float* __restrict__ out) {
  __shared__ _Float16 As[128 * 40];
  __shared__ _Float16 Bs[128 * 40];
  int m0 = blockIdx.x * 128, n0 = blockIdx.y * 128;
  int tid = threadIdx.x;
  int lane = tid & 63, wv = tid >> 6;
  int wm = (wv >> 1) * 64, wn = (wv & 1) * 64;
  int l15 = lane & 15, quad = lane >> 4;
  int srow = tid >> 1, shalf = tid & 1;
  float4v acc[4][4] = {};
  for (int k0 = 0; k0 < 512; k0 += 32) {
    __syncthreads();
    {
      const half8* ga = (const half8*)(Ain + (size_t)(m0 + srow) * 512 + k0 + shalf * 16);
      const float4* gb = (const float4*)(w + (size_t)(n0 + srow) * 512 + k0 + shalf * 16);
      half8 ha0 = ga[0], ha1 = ga[1];
      float4 b0 = gb[0], b1 = gb[1], b2 = gb[2], b3 = gb[3];
      half8 hb0 = {(_Float16)b0.x, (_Float16)b0.y, (_Float16)b0.z, (_Float16)b0.w,
                   (_Float16)b1.x, (_Float16)b1.y, (_Float16)b1.z, (_Float16)b1.w};
      half8 hb1 = {(_Float16)b2.x, (_Float16)b2.y, (_Float16)b2.z, (_Float16)b2.w,
                   (_Float16)b3.x, (_Float16)b3.y, (_Float16)b3.z, (_Float16)b3.w};
      int lo = srow * 40 + shalf * 16;
      *(half8*)&As[lo] = ha0;
      *(half8*)&As[lo + 8] = ha1;
      *(half8*)&Bs[lo] = hb0;
      *(half8*)&Bs[lo + 8] = hb1;
    }
    __syncthreads();
    half8 a[4], b[4];
#pragma unroll
    for (int mt = 0; mt < 4; ++mt)
      a[mt] = *(const half8*)&As[(wm + mt * 16 + l15) * 40 + quad * 8];
#pragma unroll
    for (int nt = 0; nt < 4; ++nt)
      b[nt] = *(const half8*)&Bs[(wn + nt * 16 + l15) * 40 + quad * 8];
#pragma unroll
    for (int mt = 0; mt < 4; ++mt)
#pragma unroll
      for (int nt = 0; nt < 4; ++nt)
        acc[mt][nt] =
            __builtin_amdgcn_mfma_f32_16x16x32_f16(a[mt], b[nt], acc[mt][nt], 0, 0, 0);
  }
#pragma unroll
  for (int mt = 0; mt < 4; ++mt) {
#pragma unroll
    for (int r = 0; r < 4; ++r) {
      int row = m0 + wm + mt * 16 + quad * 4 + r;
      int b_ = row >> 10, n_ = row & 1023;
      float t = tm[b_ * 1024 + n_];
#pragma unroll
      for (int nt = 0; nt < 4; ++nt) {
        int co = n0 + wn + nt * 16 + l15;
        out[(size_t)row * 512 + co] = (acc[mt][nt][r] + bias[co]) * t;
      }
    }
  }
}

// ---------------------------------------------------------------------------
// d_ws: 11.26 MiB high-water (proven). PS overlays dead XA/XB after ctx.
// d_out (4 MiB): W f32 (NS) -> Pbuf f16 (stats->ga) -> final f32 output.
extern "C" void kernel_launch(void* const* d_in, const int* in_sizes, int n_in,
                              void* d_out, int out_size, void* d_ws, size_t ws_size,
                              hipStream_t stream) {
  const float* x      = (const float*)d_in[0];
  const float* tm     = (const float*)d_in[1];
  const float* qkv_w  = (const float*)d_in[2];
  const float* qkv_b  = (const float*)d_in[3];
  const float* proj_w = (const float*)d_in[4];
  const float* proj_b = (const float*)d_in[5];
  const float* dwc_w  = (const float*)d_in[6];
  const float* dwc_b  = (const float*)d_in[7];
  float* out = (float*)d_out;

  char* wsb = (char*)d_ws;
  __half* Qh  = (__half*)(wsb + 0);
  __half* Kh  = (__half*)(wsb + 2097152);
  __half* Vh  = (__half*)(wsb + 4194304);
  __half* VLh = (__half*)(wsb + 6291456);
  __half* QLh = (__half*)(wsb + 8388608);
  __half* KLh = (__half*)(wsb + 8650752);
  float*  LM  = (float*)(wsb + 8912896);
  float*  MU  = (float*)(wsb + 8913920);
  float*  RS  = (float*)(wsb + 8918016);
  float*  KTV = (float*)(wsb + 8922112);
  __half* CTX = (__half*)(wsb + 9446400);
  float*  XA  = (float*)(wsb + 9708544);
  float*  XB  = (float*)(wsb + 10757120);
  float*  PS  = (float*)(wsb + 9708544);  // overlays XA+XB after ctx

  char* ob = (char*)d_out;
  float*  Wf   = (float*)ob;
  __half* Pbuf = (__half*)ob;

  qkv_gemm<<<dim3(16, 12), 256, 0, stream>>>(x, qkv_w, qkv_b, tm, Qh, Kh, Vh);
  pool_kernel<<<dim3(16, 16), 256, 0, stream>>>(Qh, Kh, tm, QLh, KLh, LM);
  wbuild_kernel<<<dim3(2, 16), 256, 0, stream>>>(QLh, KLh, LM, Wf);
  nsinit_kernel<<<16, 256, 0, stream>>>(Wf, XA);
  float* Xc = XA;
  float* Xn = XB;
  for (int it = 0; it < 5; ++it) {
    ns_iter<<<dim3(8, 16), 256, 0, stream>>>(Wf, Xc, Xn);
    float* tswap = Xc; Xc = Xn; Xn = tswap;
  }
  zero_kernel<<<512, 256, 0, stream>>>(KTV, 131072);
  ktv_fused<<<dim3(8, 16, 8), 256, 0, stream>>>(Kh, QLh, LM, Vh, KTV);
  ctx_kernel<<<dim3(32, 16), 256, 0, stream>>>(Xc, KTV, CTX);
  stats_partial<<<dim3(64, 16), 256, 0, stream>>>(Qh, KLh, LM, tm, PS, Pbuf);
  stats_final<<<4, 256, 0, stream>>>(PS, tm, MU, RS);
  vlocal_kernel<<<dim3(16, 16), 256, 0, stream>>>(Vh, dwc_w, dwc_b, tm, VLh);
  ga_fused<<<dim3(64, 16), 256, 0, stream>>>(Pbuf, MU, RS, CTX, tm, VLh);
  proj_gemm<<<dim3(16, 4), 256, 0, stream>>>(VLh, proj_w, proj_b, tm, out);
}

// Round 9
// 436.215 us; speedup vs baseline: 3.2242x; 1.0798x over previous
//
#include <hip/hip_runtime.h>
#include <hip/hip_bf16.h>
#include <hip/hip_fp16.h>

// B=2, N=1024, C=512, H=8, D=64, m=128, p=8
#define Hh 8
#define Bz 2
#define Nn 1024
#define Cc 512
#define Dd 64
#define Mm 128
#define NS_EPS 1e-4f
#define WHITE_EPS 1e-5f

__device__ __forceinline__ float h2f(__half v) { return __half2float(v); }
__device__ __forceinline__ __half f2h(float v) { return __float2half(v); }

typedef _Float16 half8 __attribute__((ext_vector_type(8)));
typedef float float4v __attribute__((ext_vector_type(4)));

// ---------------------------------------------------------------------------
// K1: QKV GEMM via MFMA f16. M=2048, N=1536, K=512. Block tile 128x128.
__global__ __launch_bounds__(256) void qkv_gemm(
    const float* __restrict__ x, const float* __restrict__ w,
    const float* __restrict__ bias, const float* __restrict__ tm,
    __half* __restrict__ Q, __half* __restrict__ K, __half* __restrict__ V) {
  __shared__ _Float16 As[128 * 40];
  __shared__ _Float16 Bs[128 * 40];
  int m0 = blockIdx.x * 128, n0 = blockIdx.y * 128;
  int tid = threadIdx.x;
  int lane = tid & 63, wv = tid >> 6;
  int wm = (wv >> 1) * 64, wn = (wv & 1) * 64;
  int l15 = lane & 15, quad = lane >> 4;
  int srow = tid >> 1, shalf = tid & 1;
  float4v acc[4][4] = {};
  for (int k0 = 0; k0 < 512; k0 += 32) {
    __syncthreads();
    {
      const float4* ga = (const float4*)(x + (size_t)(m0 + srow) * 512 + k0 + shalf * 16);
      const float4* gb = (const float4*)(w + (size_t)(n0 + srow) * 512 + k0 + shalf * 16);
      float4 a0 = ga[0], a1 = ga[1], a2 = ga[2], a3 = ga[3];
      float4 b0 = gb[0], b1 = gb[1], b2 = gb[2], b3 = gb[3];
      half8 ha0 = {(_Float16)a0.x, (_Float16)a0.y, (_Float16)a0.z, (_Float16)a0.w,
                   (_Float16)a1.x, (_Float16)a1.y, (_Float16)a1.z, (_Float16)a1.w};
      half8 ha1 = {(_Float16)a2.x, (_Float16)a2.y, (_Float16)a2.z, (_Float16)a2.w,
                   (_Float16)a3.x, (_Float16)a3.y, (_Float16)a3.z, (_Float16)a3.w};
      half8 hb0 = {(_Float16)b0.x, (_Float16)b0.y, (_Float16)b0.z, (_Float16)b0.w,
                   (_Float16)b1.x, (_Float16)b1.y, (_Float16)b1.z, (_Float16)b1.w};
      half8 hb1 = {(_Float16)b2.x, (_Float16)b2.y, (_Float16)b2.z, (_Float16)b2.w,
                   (_Float16)b3.x, (_Float16)b3.y, (_Float16)b3.z, (_Float16)b3.w};
      int lo = srow * 40 + shalf * 16;
      *(half8*)&As[lo] = ha0;
      *(half8*)&As[lo + 8] = ha1;
      *(half8*)&Bs[lo] = hb0;
      *(half8*)&Bs[lo + 8] = hb1;
    }
    __syncthreads();
    half8 a[4], b[4];
#pragma unroll
    for (int mt = 0; mt < 4; ++mt)
      a[mt] = *(const half8*)&As[(wm + mt * 16 + l15) * 40 + quad * 8];
#pragma unroll
    for (int nt = 0; nt < 4; ++nt)
      b[nt] = *(const half8*)&Bs[(wn + nt * 16 + l15) * 40 + quad * 8];
#pragma unroll
    for (int mt = 0; mt < 4; ++mt)
#pragma unroll
      for (int nt = 0; nt < 4; ++nt)
        acc[mt][nt] =
            __builtin_amdgcn_mfma_f32_16x16x32_f16(a[mt], b[nt], acc[mt][nt], 0, 0, 0);
  }
#pragma unroll
  for (int mt = 0; mt < 4; ++mt) {
#pragma unroll
    for (int r = 0; r < 4; ++r) {
      int row = m0 + wm + mt * 16 + quad * 4 + r;
      int b_ = row >> 10, n_ = row & 1023;
      float t = tm[b_ * 1024 + n_];
#pragma unroll
      for (int nt = 0; nt < 4; ++nt) {
        int c3 = n0 + wn + nt * 16 + l15;
        float v = (acc[mt][nt][r] + bias[c3]) * t;
        int sec = c3 >> 9, ch = c3 & 511;
        __half* dst = (sec == 0) ? Q : (sec == 1 ? K : V);
        dst[(size_t)b_ * (Nn * Cc) + (size_t)n_ * 512 + ch] = f2h(v);
      }
    }
  }
}

// ---------------------------------------------------------------------------
// K2: pool — block per (b,h,u-tile of 64). Coalesced row staging.
__global__ __launch_bounds__(256) void pool_kernel(
    const __half* __restrict__ Q, const __half* __restrict__ K,
    const float* __restrict__ tm, __half* __restrict__ QL,
    __half* __restrict__ KL, float* __restrict__ LM) {
  int ut = blockIdx.x;
  int bh = blockIdx.y;
  int b = bh >> 3, h = bh & 7;
  int u0 = ut * 64;
  int delta = u0 >> 9;
  int ch0 = u0 & 511;
  __shared__ float Qs[64][65];
  __shared__ float Ks[64][65];
  int tid = threadIdx.x;
  for (int e = tid; e < 4096; e += 256) {
    int d = e >> 6, uu = e & 63;
    int row = 2 * (h * 64 + d) + delta;
    size_t gi = (size_t)b * (Nn * Cc) + (size_t)row * 512 + ch0 + uu;
    Qs[d][uu] = h2f(Q[gi]);
    Ks[d][uu] = h2f(K[gi]);
  }
  __syncthreads();
  int d = tid & 63, s = tid >> 6;
#pragma unroll
  for (int jr = 0; jr < 2; ++jr) {
    int jl = s + 4 * jr;
    int j = ut * 8 + jl;
    float pm = 0.f, sq = 0.f, sk = 0.f;
#pragma unroll
    for (int i = 0; i < 8; ++i) {
      float t = tm[b * 1024 + 8 * j + i];
      pm += t;
      sq += Qs[d][8 * jl + i] * t;
      sk += Ks[d][8 * jl + i] * t;
    }
    pm *= 0.125f;
    float pms = fmaxf(pm, 1e-6f);
    size_t oi = ((size_t)bh * 128 + j) * 64 + d;
    QL[oi] = f2h(sq * 0.125f / pms);
    KL[oi] = f2h(sk * 0.125f / pms);
    if (h == 0 && d == 0) LM[b * 128 + j] = (pm > 0.f) ? 1.f : 0.f;
  }
}

// ---------------------------------------------------------------------------
// K3: W_eps[b,h,i,j] (f32, lives in d_out during NS)
__global__ __launch_bounds__(256) void wbuild_kernel(
    const __half* __restrict__ QL, const __half* __restrict__ KL,
    const float* __restrict__ LM, float* __restrict__ W) {
  int bh = blockIdx.y;
  int b = bh >> 3;
  int i0 = blockIdx.x * 64;
  __shared__ float ks[128][65];
  __shared__ float qs[64][65];
  int tid = threadIdx.x;
  const __half* klb = KL + (size_t)bh * (Mm * Dd);
  const __half* qlb = QL + (size_t)bh * (Mm * Dd);
  for (int e = tid; e < 128 * 64; e += 256) ks[e >> 6][e & 63] = h2f(klb[e]);
  for (int e = tid; e < 64 * 64; e += 256) qs[e >> 6][e & 63] = h2f(qlb[i0 * 64 + e]);
  __syncthreads();
  for (int e = tid; e < 64 * 128; e += 256) {
    int il = e >> 7, j = e & 127;
    int i = i0 + il;
    float s = 0.f;
#pragma unroll
    for (int d = 0; d < 64; ++d) s += fabsf(qs[il][d] - ks[j][d]);
    float wv = expf(-s * 0.25f);
    float pr = LM[b * Mm + i] * LM[b * Mm + j];
    float diag = (i == j) ? 1.f : 0.f;
    wv = wv * pr + diag * (1.f - pr) + diag * NS_EPS;
    W[(size_t)bh * (Mm * Mm) + i * 128 + j] = wv;
  }
}

// ---------------------------------------------------------------------------
// K4: X0 = 2/(fro+1e-8) * W^T  (f32)
__global__ __launch_bounds__(256) void nsinit_kernel(const float* __restrict__ W,
                                                     float* __restrict__ X) {
  int bh = blockIdx.x;
  const float* Wb = W + (size_t)bh * 16384;
  float* Xb = X + (size_t)bh * 16384;
  __shared__ float red[256];
  int tid = threadIdx.x;
  float s = 0.f;
  for (int e = tid; e < 16384; e += 256) { float wv = Wb[e]; s += wv * wv; }
  red[tid] = s;
  __syncthreads();
  for (int off = 128; off > 0; off >>= 1) {
    if (tid < off) red[tid] += red[tid + off];
    __syncthreads();
  }
  float scale = 2.f / (sqrtf(red[0]) + 1e-8f);
  for (int e = tid; e < 16384; e += 256) {
    int i = e >> 7, j = e & 127;
    Xb[e] = scale * Wb[j * 128 + i];
  }
}

// ---------------------------------------------------------------------------
// K5: ns_iter — Xn = Xc @ (2I - W @ Xc), 8 column-blocks of 16.
__global__ __launch_bounds__(256) void ns_iter(const float* __restrict__ W,
                                               const float* __restrict__ Xc,
                                               float* __restrict__ Xn) {
  int bh = blockIdx.y;
  int cb = blockIdx.x;  // 0..7
  const float* Wb = W + (size_t)bh * 16384;
  const float* Xb = Xc + (size_t)bh * 16384;
  float* Ob = Xn + (size_t)bh * 16384;
  __shared__ float Xs[128][17];
  __shared__ float Ts[128][17];
  __shared__ float St[128][33];
  int tid = threadIdx.x;
  int jc = tid & 15;
  int ibase = (tid >> 4) * 8;
  for (int e = tid; e < 2048; e += 256) {
    int k = e >> 4, j = e & 15;
    Xs[k][j] = Xb[(size_t)k * 128 + cb * 16 + j];
  }
  float acc[8];
#pragma unroll
  for (int r = 0; r < 8; ++r) acc[r] = 0.f;
  for (int kt = 0; kt < 4; ++kt) {
    __syncthreads();
    for (int e = tid; e < 4096; e += 256)
      St[e >> 5][e & 31] = Wb[(size_t)(e >> 5) * 128 + kt * 32 + (e & 31)];
    __syncthreads();
#pragma unroll 8
    for (int kk = 0; kk < 32; ++kk) {
      float xv = Xs[kt * 32 + kk][jc];
#pragma unroll
      for (int r = 0; r < 8; ++r) acc[r] += St[ibase + r][kk] * xv;
    }
  }
#pragma unroll
  for (int r = 0; r < 8; ++r) {
    int i = ibase + r;
    Ts[i][jc] = ((i == cb * 16 + jc) ? 2.f : 0.f) - acc[r];
  }
  float acc2[8];
#pragma unroll
  for (int r = 0; r < 8; ++r) acc2[r] = 0.f;
  for (int kt = 0; kt < 4; ++kt) {
    __syncthreads();
    for (int e = tid; e < 4096; e += 256)
      St[e >> 5][e & 31] = Xb[(size_t)(e >> 5) * 128 + kt * 32 + (e & 31)];
    __syncthreads();
#pragma unroll 8
    for (int kk = 0; kk < 32; ++kk) {
      float tv = Ts[kt * 32 + kk][jc];
#pragma unroll
      for (int r = 0; r < 8; ++r) acc2[r] += St[ibase + r][kk] * tv;
    }
  }
#pragma unroll
  for (int r = 0; r < 8; ++r)
    Ob[(size_t)(ibase + r) * 128 + cb * 16 + jc] = acc2[r];
}

// ---------------------------------------------------------------------------
// K6: zero KTV
__global__ __launch_bounds__(256) void zero_kernel(float* __restrict__ p, int n) {
  int i = blockIdx.x * 256 + threadIdx.x;
  if (i < n) p[i] = 0.f;
}

// ---------------------------------------------------------------------------
// K7: ktv v4 — fused C_k + K^T V; float4 LDS reads, register tiling.
__global__ __launch_bounds__(256) void ktv_fused(
    const __half* __restrict__ K, const __half* __restrict__ QL,
    const float* __restrict__ LM, const __half* __restrict__ V,
    float* __restrict__ KTV) {
  int jt = blockIdx.x;   // 8 (16 j each)
  int bh = blockIdx.y;   // 16
  int nc = blockIdx.z;   // 8 (128 n each)
  int b = bh >> 3, h = bh & 7;
  int j0 = jt * 16;
  __shared__ __align__(16) float qls[16 * 68];
  __shared__ __align__(16) float Ks[32 * 68];
  __shared__ __align__(16) float Vs[32 * 68];
  __shared__ float P[32 * 20];
  int tid = threadIdx.x;
  for (int e = tid; e < 1024; e += 256)
    qls[(e >> 6) * 68 + (e & 63)] =
        h2f(QL[(size_t)bh * 8192 + (size_t)(j0 + (e >> 6)) * 64 + (e & 63)]);
  int jl = tid & 15, np = tid >> 4;      // L1 phase: 2 pairs (n=2np, 2np+1; j=jl)
  int dg = tid & 15, jgv = tid >> 4;     // PV phase: d=4dg.., j=jgv
  float4 acc = {0.f, 0.f, 0.f, 0.f};
  for (int nt = 0; nt < 4; ++nt) {
    int n0 = nc * 128 + nt * 32;
    __syncthreads();
    for (int e = tid; e < 2048; e += 256) {
      int nn = e >> 6, d = e & 63;
      size_t gi = (size_t)b * (Nn * Cc) + (size_t)(n0 + nn) * 512 + h * 64 + d;
      Ks[nn * 68 + d] = h2f(K[gi]);
      Vs[nn * 68 + d] = h2f(V[gi]);
    }
    __syncthreads();
    {
      const float4* qp = (const float4*)&qls[jl * 68];
      const float4* kA = (const float4*)&Ks[(np * 2) * 68];
      const float4* kB = (const float4*)&Ks[(np * 2 + 1) * 68];
      float sA = 0.f, sB = 0.f;
#pragma unroll
      for (int i = 0; i < 16; ++i) {
        int dq = (i + tid) & 15;
        float4 qv = qp[dq];
        float4 a = kA[dq];
        float4 bb = kB[dq];
        sA += fabsf(qv.x - a.x) + fabsf(qv.y - a.y) + fabsf(qv.z - a.z) + fabsf(qv.w - a.w);
        sB += fabsf(qv.x - bb.x) + fabsf(qv.y - bb.y) + fabsf(qv.z - bb.z) + fabsf(qv.w - bb.w);
      }
      P[(np * 2) * 20 + jl] = expf(-sA * 0.25f);
      P[(np * 2 + 1) * 20 + jl] = expf(-sB * 0.25f);
    }
    __syncthreads();
    {
#pragma unroll 8
      for (int n = 0; n < 32; ++n) {
        float pv = P[n * 20 + jgv];
        float4 vv = *(const float4*)&Vs[n * 68 + dg * 4];
        acc.x += pv * vv.x; acc.y += pv * vv.y;
        acc.z += pv * vv.z; acc.w += pv * vv.w;
      }
    }
  }
  {
    float lm = LM[b * 128 + j0 + jgv];
    float* dst = &KTV[(size_t)bh * 8192 + (size_t)(j0 + jgv) * 64 + dg * 4];
    atomicAdd(dst + 0, acc.x * lm);
    atomicAdd(dst + 1, acc.y * lm);
    atomicAdd(dst + 2, acc.z * lm);
    atomicAdd(dst + 3, acc.w * lm);
  }
}

// ---------------------------------------------------------------------------
// K8: CTX[bh,i,d] = sum_j X[bh,i,j] * KTV[bh,j,d]  (f32 in, f16 out)
__global__ __launch_bounds__(256) void ctx_kernel(const float* __restrict__ X,
                                                  const float* __restrict__ KTV,
                                                  __half* __restrict__ CTX) {
  int bh = blockIdx.y;
  int i = blockIdx.x * 4 + (threadIdx.x >> 6);
  int d = threadIdx.x & 63;
  const float* wb = X + (size_t)bh * 16384 + (size_t)i * 128;
  const float* kb = KTV + (size_t)bh * 8192 + d;
  float acc = 0.f;
#pragma unroll 4
  for (int jj = 0; jj < 128; ++jj) acc += wb[jj] * kb[(size_t)jj * 64];
  CTX[(size_t)bh * 8192 + (size_t)i * 64 + d] = f2h(acc);
}

// ---------------------------------------------------------------------------
// K9: stats_partial v3 — float4 LDS reads, 2j x 4n register tile.
__global__ __launch_bounds__(256) void stats_partial(
    const __half* __restrict__ Q, const __half* __restrict__ KL,
    const float* __restrict__ LM, const float* __restrict__ tm,
    float* __restrict__ PS, __half* __restrict__ Pbuf) {
  int nt = blockIdx.x;   // 64
  int bh = blockIdx.y;   // 16
  int b = bh >> 3, h = bh & 7;
  int n0 = nt * 16;
  __shared__ __align__(16) float kls[128 * 68];
  __shared__ __align__(16) float qs[16 * 68];
  __shared__ __half ps[16 * 132];
  __shared__ float part[128 * 12];  // [j][ng][3]
  int tid = threadIdx.x;
  for (int e = tid; e < 8192; e += 256)
    kls[(e >> 6) * 68 + (e & 63)] = h2f(KL[(size_t)bh * 8192 + e]);
  for (int e = tid; e < 1024; e += 256)
    qs[(e >> 6) * 68 + (e & 63)] =
        h2f(Q[(size_t)b * (Nn * Cc) + (size_t)(n0 + (e >> 6)) * 512 + h * 64 + (e & 63)]);
  __syncthreads();
  int jg = tid & 63, ng = tid >> 6;
  int j = jg * 2;
  const float4* kA = (const float4*)&kls[j * 68];
  const float4* kB = (const float4*)&kls[(j + 1) * 68];
  float sA[4] = {}, sB[4] = {};
#pragma unroll
  for (int i = 0; i < 16; ++i) {
    int dq = (i + jg) & 15;
    float4 ka = kA[dq];
    float4 kb = kB[dq];
#pragma unroll
    for (int r = 0; r < 4; ++r) {
      float4 qv = *(const float4*)&qs[(ng * 4 + r) * 68 + dq * 4];
      sA[r] += fabsf(qv.x - ka.x) + fabsf(qv.y - ka.y) + fabsf(qv.z - ka.z) + fabsf(qv.w - ka.w);
      sB[r] += fabsf(qv.x - kb.x) + fabsf(qv.y - kb.y) + fabsf(qv.z - kb.z) + fabsf(qv.w - kb.w);
    }
  }
  float lmA = LM[b * 128 + j], lmB = LM[b * 128 + j + 1];
  float a1 = 0.f, a2 = 0.f, a3 = 0.f, b1 = 0.f, b2 = 0.f, b3 = 0.f;
#pragma unroll
  for (int r = 0; r < 4; ++r) {
    int nn = ng * 4 + r;
    float t = tm[b * 1024 + n0 + nn];
    float xa = expf(-sA[r] * 0.25f) * lmA;
    float xb = expf(-sB[r] * 0.25f) * lmB;
    ps[nn * 132 + j] = f2h(xa);
    ps[nn * 132 + j + 1] = f2h(xb);
    float xta = xa * t, xtb = xb * t;
    a1 += xta; a2 += xta * xta; a3 += xta * t;
    b1 += xtb; b2 += xtb * xtb; b3 += xtb * t;
  }
  part[j * 12 + ng * 3 + 0] = a1;
  part[j * 12 + ng * 3 + 1] = a2;
  part[j * 12 + ng * 3 + 2] = a3;
  part[(j + 1) * 12 + ng * 3 + 0] = b1;
  part[(j + 1) * 12 + ng * 3 + 1] = b2;
  part[(j + 1) * 12 + ng * 3 + 2] = b3;
  __syncthreads();
  for (int e = tid; e < 2048; e += 256)
    Pbuf[((size_t)bh * 1024 + n0 + (e >> 7)) * 128 + (e & 127)] =
        ps[(e >> 7) * 132 + (e & 127)];
  if (tid < 128) {
    float s1 = part[tid * 12 + 0] + part[tid * 12 + 3] + part[tid * 12 + 6] + part[tid * 12 + 9];
    float s2 = part[tid * 12 + 1] + part[tid * 12 + 4] + part[tid * 12 + 7] + part[tid * 12 + 10];
    float s3 = part[tid * 12 + 2] + part[tid * 12 + 5] + part[tid * 12 + 8] + part[tid * 12 + 11];
    size_t base = ((size_t)(b * 64 + nt) * 8 + h) * 384 + tid * 3;
    PS[base] = s1; PS[base + 1] = s2; PS[base + 2] = s3;
  }
}

// ---------------------------------------------------------------------------
// K10: stats_final — reduce PS over 128 (b,nt) tiles per (h,j).
__global__ __launch_bounds__(256) void stats_final(const float* __restrict__ PS,
                                                   const float* __restrict__ tm,
                                                   float* __restrict__ MU,
                                                   float* __restrict__ RS) {
  __shared__ float red[256][2];
  __shared__ float ts0, ts1;
  int tid = threadIdx.x;
  float a = 0.f, c = 0.f;
  for (int i = tid; i < 2048; i += 256) { float t = tm[i]; a += t; c += t * t; }
  red[tid][0] = a; red[tid][1] = c;
  __syncthreads();
  for (int off = 128; off > 0; off >>= 1) {
    if (tid < off) { red[tid][0] += red[tid + off][0]; red[tid][1] += red[tid + off][1]; }
    __syncthreads();
  }
  if (tid == 0) { ts0 = red[0][0]; ts1 = red[0][1]; }
  __syncthreads();
  int hj = blockIdx.x * 256 + tid;
  int h = hj >> 7, j = hj & 127;
  float s1 = 0.f, s2 = 0.f, s3 = 0.f;
  for (int bnt = 0; bnt < 128; ++bnt) {
    const float* p = PS + ((size_t)bnt * 8 + h) * 384 + j * 3;
    s1 += p[0]; s2 += p[1]; s3 += p[2];
  }
  float valid = fmaxf(ts0, 1.f);
  float mu = s1 / valid;
  float var = (s2 - 2.f * mu * s3 + mu * mu * ts1) / valid;
  var = fmaxf(var, 0.f);
  MU[hj] = mu;
  RS[hj] = rsqrtf(var + WHITE_EPS);
}

// ---------------------------------------------------------------------------
// K11: vlocal — LDS-tiled scrambled depthwise conv.
__global__ __launch_bounds__(256) void vlocal_kernel(
    const __half* __restrict__ V, const float* __restrict__ dwc_w,
    const float* __restrict__ dwc_b, const float* __restrict__ tm,
    __half* __restrict__ VL) {
  int t0 = blockIdx.x * 64;
  int ct = blockIdx.y & 7, b = blockIdx.y >> 3;
  int c0 = ct * 64;
  __shared__ float vs[64][67];
  int tid = threadIdx.x;
  for (int e = tid; e < 64 * 66; e += 256) {
    int cl = e / 66, uu = e % 66;
    int u = t0 - 1 + uu;
    float val = 0.f;
    if (u >= 0 && u < 1024) {
      int c = c0 + cl;
      int n = 2 * c + (u >> 9), ch = u & 511;
      val = h2f(V[(size_t)b * (Nn * Cc) + (size_t)n * 512 + ch]);
    }
    vs[cl][uu] = val;
  }
  __syncthreads();
  int cl = tid & 63;
  int c = c0 + cl;
  float w0 = dwc_w[c * 3], w1 = dwc_w[c * 3 + 1], w2 = dwc_w[c * 3 + 2];
  float bb = dwc_b[c];
  int tg = tid >> 6;
#pragma unroll
  for (int i = 0; i < 16; ++i) {
    int tl = tg * 16 + i;
    int t = t0 + tl;
    float acc = bb + w0 * vs[cl][tl] + w1 * vs[cl][tl + 1] + w2 * vs[cl][tl + 2];
    VL[(size_t)b * (Nn * Cc) + (size_t)t * 512 + c] = f2h(acc * tm[b * 1024 + t]);
  }
}

// ---------------------------------------------------------------------------
// K12: ga — load precomputed P, whiten, @context, accumulate into VL.
__global__ __launch_bounds__(256) void ga_fused(
    const __half* __restrict__ Pbuf, const float* __restrict__ MU,
    const float* __restrict__ RS, const __half* __restrict__ CTXg,
    const float* __restrict__ tm, __half* __restrict__ VL) {
  int bh = blockIdx.y;
  int b = bh >> 3, h = bh & 7;
  int n0 = blockIdx.x * 16;
  __shared__ __half Ps[16][130];
  __shared__ __half2 ctx2[128][32];
  __shared__ float musr[128][2];
  int tid = threadIdx.x;
  for (int e = tid; e < 2048; e += 256)
    Ps[e >> 7][e & 127] = Pbuf[((size_t)bh * 1024 + n0 + (e >> 7)) * 128 + (e & 127)];
  {
    const __half2* cg = (const __half2*)(CTXg + (size_t)bh * 8192);
    for (int e = tid; e < 4096; e += 256) ctx2[e >> 5][e & 31] = cg[e];
  }
  if (tid < 128) { musr[tid][0] = MU[h * 128 + tid]; musr[tid][1] = RS[h * 128 + tid]; }
  __syncthreads();
  int nn = tid >> 4, dq = tid & 15;
  float a0 = 0.f, a1 = 0.f, a2 = 0.f, a3 = 0.f;
#pragma unroll 4
  for (int j = 0; j < 128; ++j) {
    float pj = (h2f(Ps[nn][j]) - musr[j][0]) * musr[j][1];
    __half2 c01 = ctx2[j][dq * 2];
    __half2 c23 = ctx2[j][dq * 2 + 1];
    a0 += pj * h2f(c01.x); a1 += pj * h2f(c01.y);
    a2 += pj * h2f(c23.x); a3 += pj * h2f(c23.y);
  }
  float t = tm[b * 1024 + n0 + nn];
  float t2 = t * t;
  size_t base = (size_t)b * (Nn * Cc) + (size_t)(n0 + nn) * 512 + h * 64 + dq * 4;
  VL[base] = f2h(h2f(VL[base]) + t2 * a0);
  VL[base + 1] = f2h(h2f(VL[base + 1]) + t2 * a1);
  VL[base + 2] = f2h(h2f(VL[base + 2]) + t2 * a2);
  VL[base + 3] = f2h(h2f(VL[base + 3]) + t2 * a3);
}

// ---------------------------------------------------------------------------
// K13: proj via MFMA f16. M=2048, N=512, K=512.
__global__ __launch_bounds__(256) void proj_gemm(
    const __half* __restrict__ Ain, const float* __restrict__ w,
    const float* __restrict__ bias, const float* __restrict__ tm,
    float* __restrict__ out) {
  __shared__ _Float16 As[128 * 40];
  __shared__ _Float16 Bs[128 * 40];
  int m0 = blockIdx.x * 128, n0 = blockIdx.y * 128;
  int tid = threadIdx.x;
  int lane = tid & 63, wv = tid >> 6;
  int wm = (wv >> 1) * 64, wn = (wv & 1) * 64;
  int l15 = lane & 15, quad = lane >> 4;
  int srow = tid >> 1, shalf = tid & 1;
  float4v acc[4][4] = {};
  for (int k0 = 0; k0 < 512; k0 += 32) {
    __syncthreads();
    {
      const half8* ga = (const half8*)(Ain + (size_t)(m0 + srow) * 512 + k0 + shalf * 16);
      const float4* gb = (const float4*)(w + (size_t)(n0 + srow) * 512 + k0 + shalf * 16);
      half8 ha0 = ga[0], ha1 = ga[1];
      float4 b0 = gb[0], b1 = gb[1], b2 = gb[2], b3 = gb[3];
      half8 hb0 = {(_Float16)b0.x, (_Float16)b0.y, (_Float16)b0.z, (_Float16)b0.w,
                   (_Float16)b1.x, (_Float16)b1.y, (_Float16)b1.z, (_Float16)b1.w};
      half8 hb1 = {(_Float16)b2.x, (_Float16)b2.y, (_Float16)b2.z, (_Float16)b2.w,
                   (_Float16)b3.x, (_Float16)b3.y, (_Float16)b3.z, (_Float16)b3.w};
      int lo = srow * 40 + shalf * 16;
      *(half8*)&As[lo] = ha0;
      *(half8*)&As[lo + 8] = ha1;
      *(half8*)&Bs[lo] = hb0;
      *(half8*)&Bs[lo + 8] = hb1;
    }
    __syncthreads();
    half8 a[4], b[4];
#pragma unroll
    for (int mt = 0; mt < 4; ++mt)
      a[mt] = *(const half8*)&As[(wm + mt * 16 + l15) * 40 + quad * 8];
#pragma unroll
    for (int nt = 0; nt < 4; ++nt)
      b[nt] = *(const half8*)&Bs[(wn + nt * 16 + l15) * 40 + quad * 8];
#pragma unroll
    for (int mt = 0; mt < 4; ++mt)
#pragma unroll
      for (int nt = 0; nt < 4; ++nt)
        acc[mt][nt] =
            __builtin_amdgcn_mfma_f32_16x16x32_f16(a[mt], b[nt], acc[mt][nt], 0, 0, 0);
  }
#pragma unroll
  for (int mt = 0; mt < 4; ++mt) {
#pragma unroll
    for (int r = 0; r < 4; ++r) {
      int row = m0 + wm + mt * 16 + quad * 4 + r;
      int b_ = row >> 10, n_ = row & 1023;
      float t = tm[b_ * 1024 + n_];
#pragma unroll
      for (int nt = 0; nt < 4; ++nt) {
        int co = n0 + wn + nt * 16 + l15;
        out[(size_t)row * 512 + co] = (acc[mt][nt][r] + bias[co]) * t;
      }
    }
  }
}

// ---------------------------------------------------------------------------
extern "C" void kernel_launch(void* const* d_in, const int* in_sizes, int n_in,
                              void* d_out, int out_size, void* d_ws, size_t ws_size,
                              hipStream_t stream) {
  const float* x      = (const float*)d_in[0];
  const float* tm     = (const float*)d_in[1];
  const float* qkv_w  = (const float*)d_in[2];
  const float* qkv_b  = (const float*)d_in[3];
  const float* proj_w = (const float*)d_in[4];
  const float* proj_b = (const float*)d_in[5];
  const float* dwc_w  = (const float*)d_in[6];
  const float* dwc_b  = (const float*)d_in[7];
  float* out = (float*)d_out;

  char* wsb = (char*)d_ws;
  __half* Qh  = (__half*)(wsb + 0);
  __half* Kh  = (__half*)(wsb + 2097152);
  __half* Vh  = (__half*)(wsb + 4194304);
  __half* VLh = (__half*)(wsb + 6291456);
  __half* QLh = (__half*)(wsb + 8388608);
  __half* KLh = (__half*)(wsb + 8650752);
  float*  LM  = (float*)(wsb + 8912896);
  float*  MU  = (float*)(wsb + 8913920);
  float*  RS  = (float*)(wsb + 8918016);
  float*  KTV = (float*)(wsb + 8922112);
  __half* CTX = (__half*)(wsb + 9446400);
  float*  XA  = (float*)(wsb + 9708544);
  float*  XB  = (float*)(wsb + 10757120);
  float*  PS  = (float*)(wsb + 9708544);  // overlays XA+XB after ctx

  char* ob = (char*)d_out;
  float*  Wf   = (float*)ob;
  __half* Pbuf = (__half*)ob;

  qkv_gemm<<<dim3(16, 12), 256, 0, stream>>>(x, qkv_w, qkv_b, tm, Qh, Kh, Vh);
  pool_kernel<<<dim3(16, 16), 256, 0, stream>>>(Qh, Kh, tm, QLh, KLh, LM);
  wbuild_kernel<<<dim3(2, 16), 256, 0, stream>>>(QLh, KLh, LM, Wf);
  nsinit_kernel<<<16, 256, 0, stream>>>(Wf, XA);
  float* Xc = XA;
  float* Xn = XB;
  for (int it = 0; it < 5; ++it) {
    ns_iter<<<dim3(8, 16), 256, 0, stream>>>(Wf, Xc, Xn);
    float* tswap = Xc; Xc = Xn; Xn = tswap;
  }
  zero_kernel<<<512, 256, 0, stream>>>(KTV, 131072);
  ktv_fused<<<dim3(8, 16, 8), 256, 0, stream>>>(Kh, QLh, LM, Vh, KTV);
  ctx_kernel<<<dim3(32, 16), 256, 0, stream>>>(Xc, KTV, CTX);
  stats_partial<<<dim3(64, 16), 256, 0, stream>>>(Qh, KLh, LM, tm, PS, Pbuf);
  stats_final<<<4, 256, 0, stream>>>(PS, tm, MU, RS);
  vlocal_kernel<<<dim3(16, 16), 256, 0, stream>>>(Vh, dwc_w, dwc_b, tm, VLh);
  ga_fused<<<dim3(64, 16), 256, 0, stream>>>(Pbuf, MU, RS, CTX, tm, VLh);
  proj_gemm<<<dim3(16, 4), 256, 0, stream>>>(VLh, proj_w, proj_b, tm, out);
}